// Round 2
// baseline (7407.602 us; speedup 1.0000x reference)
//
#include <hip/hip_runtime.h>
#include <math.h>

#define EDIM 1024
#define HN 16
#define HD 64
#define SEQ 2048
#define BATCH 4
#define FFD 4096
#define NTOK (BATCH*SEQ)

// ---------------------------------------------------------------------------
// Kernel 1: fused LayerNorm(g1,b1) of q/k/v rows + per-head 64x64 projection.
// One block per token. LDS stride 68 (pad) for conflict-free float4 reads.
// ---------------------------------------------------------------------------
__device__ __forceinline__ void proj_stage(const float* __restrict__ Wg,
                                           const float* xlds, float* wbuf,
                                           float* __restrict__ outp,
                                           size_t tE, int tid)
{
  for (int idx = tid; idx < HD * HD; idx += 256)
    wbuf[(idx >> 6) * 68 + (idx & 63)] = Wg[idx];
  __syncthreads();
  const int i = tid >> 2;      // 0..63 output row within head
  const int g = tid & 3;       // head group
  const float4* wr = (const float4*)(wbuf + i * 68);
#pragma unroll
  for (int hh = 0; hh < 4; ++hh) {
    const int h = g * 4 + hh;
    const float4* xr = (const float4*)(xlds + h * 68);
    float acc = 0.f;
#pragma unroll
    for (int j4 = 0; j4 < 16; ++j4) {
      float4 w = wr[j4], x = xr[j4];
      acc += w.x * x.x + w.y * x.y + w.z * x.z + w.w * x.w;
    }
    outp[tE + h * 64 + i] = acc;
  }
  __syncthreads();
}

__global__ __launch_bounds__(256) void k_ln_qkv(
    const float* __restrict__ qin, const float* __restrict__ kin,
    const float* __restrict__ vin, const float* __restrict__ g1,
    const float* __restrict__ b1, const float* __restrict__ Wq,
    const float* __restrict__ Wk, const float* __restrict__ Wv,
    float* __restrict__ qp, float* __restrict__ kp, float* __restrict__ vp)
{
  __shared__ float xq[HN * 68], xk[HN * 68], xv[HN * 68];
  __shared__ float wbuf[HD * 68];
  __shared__ float red[4][6];
  const int tid = threadIdx.x;
  const size_t tE = (size_t)blockIdx.x * EDIM;

  float4 aq = ((const float4*)(qin + tE))[tid];
  float4 ak = ((const float4*)(kin + tE))[tid];
  float4 av = ((const float4*)(vin + tE))[tid];

  float sq = aq.x + aq.y + aq.z + aq.w;
  float ssq = aq.x * aq.x + aq.y * aq.y + aq.z * aq.z + aq.w * aq.w;
  float sk = ak.x + ak.y + ak.z + ak.w;
  float ssk = ak.x * ak.x + ak.y * ak.y + ak.z * ak.z + ak.w * ak.w;
  float sv = av.x + av.y + av.z + av.w;
  float ssv = av.x * av.x + av.y * av.y + av.z * av.z + av.w * av.w;
#pragma unroll
  for (int off = 32; off; off >>= 1) {
    sq += __shfl_down(sq, off);   ssq += __shfl_down(ssq, off);
    sk += __shfl_down(sk, off);   ssk += __shfl_down(ssk, off);
    sv += __shfl_down(sv, off);   ssv += __shfl_down(ssv, off);
  }
  if ((tid & 63) == 0) {
    const int w = tid >> 6;
    red[w][0] = sq; red[w][1] = ssq; red[w][2] = sk;
    red[w][3] = ssk; red[w][4] = sv; red[w][5] = ssv;
  }
  __syncthreads();
  sq = red[0][0] + red[1][0] + red[2][0] + red[3][0];
  ssq = red[0][1] + red[1][1] + red[2][1] + red[3][1];
  sk = red[0][2] + red[1][2] + red[2][2] + red[3][2];
  ssk = red[0][3] + red[1][3] + red[2][3] + red[3][3];
  sv = red[0][4] + red[1][4] + red[2][4] + red[3][4];
  ssv = red[0][5] + red[1][5] + red[2][5] + red[3][5];

  const float rE = 1.f / EDIM;
  const float muq = sq * rE, muk = sk * rE, muv = sv * rE;
  const float ivq = rsqrtf(ssq * rE - muq * muq + 1e-5f);
  const float ivk = rsqrtf(ssk * rE - muk * muk + 1e-5f);
  const float ivv = rsqrtf(ssv * rE - muv * muv + 1e-5f);

  float4 gg = ((const float4*)g1)[tid];
  float4 bb = ((const float4*)b1)[tid];
  const int j = tid * 4;
  float* dq = xq + (j >> 6) * 68 + (j & 63);
  float* dk = xk + (j >> 6) * 68 + (j & 63);
  float* dv = xv + (j >> 6) * 68 + (j & 63);
  dq[0] = (aq.x - muq) * ivq * gg.x + bb.x;
  dq[1] = (aq.y - muq) * ivq * gg.y + bb.y;
  dq[2] = (aq.z - muq) * ivq * gg.z + bb.z;
  dq[3] = (aq.w - muq) * ivq * gg.w + bb.w;
  dk[0] = (ak.x - muk) * ivk * gg.x + bb.x;
  dk[1] = (ak.y - muk) * ivk * gg.y + bb.y;
  dk[2] = (ak.z - muk) * ivk * gg.z + bb.z;
  dk[3] = (ak.w - muk) * ivk * gg.w + bb.w;
  dv[0] = (av.x - muv) * ivv * gg.x + bb.x;
  dv[1] = (av.y - muv) * ivv * gg.y + bb.y;
  dv[2] = (av.z - muv) * ivv * gg.z + bb.z;
  dv[3] = (av.w - muv) * ivv * gg.w + bb.w;
  __syncthreads();

  proj_stage(Wq, xq, wbuf, qp, tE, tid);
  proj_stage(Wk, xk, wbuf, kp, tE, tid);
  proj_stage(Wv, xv, wbuf, vp, tE, tid);
}

// ---------------------------------------------------------------------------
// Kernel 2: flash attention, fp32. Block = (b, h, 64 q rows); 64-key tiles.
// ALiBi bias + mask applied pre-scale (1/sqrt(E)=1/32), online softmax.
// P tile aliases the K tile (extra barrier) to stay < 64 KB LDS.
// ---------------------------------------------------------------------------
__global__ __launch_bounds__(256) void k_attn(
    const float* __restrict__ qp, const float* __restrict__ kp,
    const float* __restrict__ vp, const int* __restrict__ mask,
    float* __restrict__ ao)
{
  __shared__ float Qs[64 * 68];
  __shared__ float KPs[64 * 68];   // K tile, reused as P tile
  __shared__ float Vs[64 * 68];
  __shared__ int Ms[64];
  const int tid = threadIdx.x;
  const int qg = tid >> 4;   // 0..15 -> q rows qg*4..+3
  const int kg = tid & 15;   // 0..15 -> key cols kg*4..+3 (and O cols kg*4..+3)
  const int qt = blockIdx.x, h = blockIdx.y, b = blockIdx.z;
  const int qbase = qt * 64;
  const float slope = exp2f(-(float)(h + 1));
  const size_t bhbase = ((size_t)b * SEQ) * EDIM + h * HD;

  for (int idx = tid; idx < 64 * 16; idx += 256) {
    int row = idx >> 4, c4 = idx & 15;
    *(float4*)(Qs + row * 68 + c4 * 4) =
        *(const float4*)(qp + bhbase + (size_t)(qbase + row) * EDIM + c4 * 4);
  }

  float m[4], l[4];
  float4 acc[4];
#pragma unroll
  for (int i = 0; i < 4; ++i) {
    m[i] = -1e30f; l[i] = 0.f; acc[i] = make_float4(0.f, 0.f, 0.f, 0.f);
  }

  for (int kt = 0; kt < SEQ / 64; ++kt) {
    const int kbase = kt * 64;
    __syncthreads();
    for (int idx = tid; idx < 64 * 16; idx += 256) {
      int row = idx >> 4, c4 = idx & 15;
      *(float4*)(KPs + row * 68 + c4 * 4) =
          *(const float4*)(kp + bhbase + (size_t)(kbase + row) * EDIM + c4 * 4);
      *(float4*)(Vs + row * 68 + c4 * 4) =
          *(const float4*)(vp + bhbase + (size_t)(kbase + row) * EDIM + c4 * 4);
    }
    if (tid < 64) Ms[tid] = mask[b * SEQ + kbase + tid];
    __syncthreads();

    // 4x4 register-tiled scores
    float sc[4][4];
#pragma unroll
    for (int i = 0; i < 4; ++i) { sc[i][0] = sc[i][1] = sc[i][2] = sc[i][3] = 0.f; }
#pragma unroll
    for (int d4 = 0; d4 < 16; ++d4) {
      float4 qv[4], kv[4];
#pragma unroll
      for (int i = 0; i < 4; ++i)
        qv[i] = *(const float4*)(Qs + (qg * 4 + i) * 68 + d4 * 4);
#pragma unroll
      for (int jn = 0; jn < 4; ++jn)
        kv[jn] = *(const float4*)(KPs + (kg * 4 + jn) * 68 + d4 * 4);
#pragma unroll
      for (int i = 0; i < 4; ++i)
#pragma unroll
        for (int jn = 0; jn < 4; ++jn)
          sc[i][jn] += qv[i].x * kv[jn].x + qv[i].y * kv[jn].y +
                       qv[i].z * kv[jn].z + qv[i].w * kv[jn].w;
    }
    __syncthreads();   // all K reads done; KPs may become P

#pragma unroll
    for (int i = 0; i < 4; ++i) {
      const int qi = qbase + qg * 4 + i;
      float tm = -1e30f;
#pragma unroll
      for (int jn = 0; jn < 4; ++jn) {
        const int kj = kbase + kg * 4 + jn;
        float s = Ms[kg * 4 + jn] ? (sc[i][jn] - slope * fabsf((float)(qi - kj)))
                                  : -1e4f;
        s *= 0.03125f;   // 1/sqrt(E)
        sc[i][jn] = s;
        tm = fmaxf(tm, s);
      }
      tm = fmaxf(tm, __shfl_xor(tm, 1));
      tm = fmaxf(tm, __shfl_xor(tm, 2));
      tm = fmaxf(tm, __shfl_xor(tm, 4));
      tm = fmaxf(tm, __shfl_xor(tm, 8));
      const float mn = fmaxf(m[i], tm);
      const float corr = __expf(m[i] - mn);
      float ps = 0.f;
#pragma unroll
      for (int jn = 0; jn < 4; ++jn) {
        const float p = __expf(sc[i][jn] - mn);
        KPs[(qg * 4 + i) * 68 + kg * 4 + jn] = p;
        ps += p;
      }
      ps += __shfl_xor(ps, 1); ps += __shfl_xor(ps, 2);
      ps += __shfl_xor(ps, 4); ps += __shfl_xor(ps, 8);
      l[i] = l[i] * corr + ps;
      m[i] = mn;
      acc[i].x *= corr; acc[i].y *= corr; acc[i].z *= corr; acc[i].w *= corr;
    }
    __syncthreads();   // P visible

#pragma unroll 8
    for (int k = 0; k < 64; ++k) {
      const float4 vv = *(const float4*)(Vs + k * 68 + kg * 4);
#pragma unroll
      for (int i = 0; i < 4; ++i) {
        const float p = KPs[(qg * 4 + i) * 68 + k];
        acc[i].x = fmaf(p, vv.x, acc[i].x);
        acc[i].y = fmaf(p, vv.y, acc[i].y);
        acc[i].z = fmaf(p, vv.z, acc[i].z);
        acc[i].w = fmaf(p, vv.w, acc[i].w);
      }
    }
  }

#pragma unroll
  for (int i = 0; i < 4; ++i) {
    const float inv = 1.f / l[i];
    float4 o;
    o.x = acc[i].x * inv; o.y = acc[i].y * inv;
    o.z = acc[i].z * inv; o.w = acc[i].w * inv;
    *(float4*)(ao + bhbase + (size_t)(qbase + qg * 4 + i) * EDIM + kg * 4) = o;
  }
}

// ---------------------------------------------------------------------------
// Kernel 3: fp32 GEMM  out[M,1024] = A[M,K] @ W[1024,K]^T + bias + resid.
// Tile 128x128, K-step 16, 8x8 per thread (64 FMA per 4 ds_read_b128).
// ---------------------------------------------------------------------------
__global__ __launch_bounds__(256) void k_gemm_nres(
    const float* __restrict__ A, const float* __restrict__ W,
    const float* __restrict__ bias, const float* __restrict__ resid,
    float* __restrict__ out, int K)
{
  __shared__ float As[16][132];
  __shared__ float Bs[16][132];
  const int tid = threadIdx.x;
  const int m0 = blockIdx.y * 128;
  const int n0 = blockIdx.x * 128;
  const int tr = tid >> 4;   // 0..15 -> rows tr*8..+7
  const int tc = tid & 15;   // 0..15 -> cols tc*8..+7
  float acc[8][8] = {};

  for (int k0 = 0; k0 < K; k0 += 16) {
    __syncthreads();
#pragma unroll
    for (int u = 0; u < 2; ++u) {
      const int f = tid * 2 + u;          // 0..511
      const int row = f >> 2, kq = f & 3;
      float4 a = *(const float4*)(A + (size_t)(m0 + row) * K + k0 + kq * 4);
      As[kq * 4 + 0][row] = a.x; As[kq * 4 + 1][row] = a.y;
      As[kq * 4 + 2][row] = a.z; As[kq * 4 + 3][row] = a.w;
      float4 bv = *(const float4*)(W + (size_t)(n0 + row) * K + k0 + kq * 4);
      Bs[kq * 4 + 0][row] = bv.x; Bs[kq * 4 + 1][row] = bv.y;
      Bs[kq * 4 + 2][row] = bv.z; Bs[kq * 4 + 3][row] = bv.w;
    }
    __syncthreads();
#pragma unroll
    for (int kk = 0; kk < 16; ++kk) {
      float4 a0 = *(const float4*)(&As[kk][tr * 8]);
      float4 a1 = *(const float4*)(&As[kk][tr * 8 + 4]);
      float4 b0 = *(const float4*)(&Bs[kk][tc * 8]);
      float4 b1 = *(const float4*)(&Bs[kk][tc * 8 + 4]);
      const float ar[8] = {a0.x, a0.y, a0.z, a0.w, a1.x, a1.y, a1.z, a1.w};
      const float br[8] = {b0.x, b0.y, b0.z, b0.w, b1.x, b1.y, b1.z, b1.w};
#pragma unroll
      for (int ii = 0; ii < 8; ++ii)
#pragma unroll
        for (int jj = 0; jj < 8; ++jj)
          acc[ii][jj] = fmaf(ar[ii], br[jj], acc[ii][jj]);
    }
  }

  const float4 bva = *(const float4*)(bias + n0 + tc * 8);
  const float4 bvb = *(const float4*)(bias + n0 + tc * 8 + 4);
#pragma unroll
  for (int ii = 0; ii < 8; ++ii) {
    const int row = m0 + tr * 8 + ii;
    const float4 r0 = *(const float4*)(resid + (size_t)row * EDIM + n0 + tc * 8);
    const float4 r1 = *(const float4*)(resid + (size_t)row * EDIM + n0 + tc * 8 + 4);
    float4 o0, o1;
    o0.x = acc[ii][0] + bva.x + r0.x;
    o0.y = acc[ii][1] + bva.y + r0.y;
    o0.z = acc[ii][2] + bva.z + r0.z;
    o0.w = acc[ii][3] + bva.w + r0.w;
    o1.x = acc[ii][4] + bvb.x + r1.x;
    o1.y = acc[ii][5] + bvb.y + r1.y;
    o1.z = acc[ii][6] + bvb.z + r1.z;
    o1.w = acc[ii][7] + bvb.w + r1.w;
    *(float4*)(out + (size_t)row * EDIM + n0 + tc * 8) = o0;
    *(float4*)(out + (size_t)row * EDIM + n0 + tc * 8 + 4) = o1;
  }
}

// ---------------------------------------------------------------------------
// Kernel 4: LayerNorm (one block per token)
// ---------------------------------------------------------------------------
__global__ __launch_bounds__(256) void k_ln(
    const float* __restrict__ x, const float* __restrict__ g,
    const float* __restrict__ bb, float* __restrict__ y)
{
  __shared__ float red[4][2];
  const int tid = threadIdx.x;
  const size_t tE = (size_t)blockIdx.x * EDIM;
  float4 v = ((const float4*)(x + tE))[tid];
  float s = v.x + v.y + v.z + v.w;
  float ss = v.x * v.x + v.y * v.y + v.z * v.z + v.w * v.w;
#pragma unroll
  for (int off = 32; off; off >>= 1) {
    s += __shfl_down(s, off); ss += __shfl_down(ss, off);
  }
  if ((tid & 63) == 0) { red[tid >> 6][0] = s; red[tid >> 6][1] = ss; }
  __syncthreads();
  s = red[0][0] + red[1][0] + red[2][0] + red[3][0];
  ss = red[0][1] + red[1][1] + red[2][1] + red[3][1];
  const float mu = s * (1.f / EDIM);
  const float inv = rsqrtf(ss * (1.f / EDIM) - mu * mu + 1e-5f);
  float4 gg = ((const float4*)g)[tid];
  float4 b4 = ((const float4*)bb)[tid];
  float4 o;
  o.x = (v.x - mu) * inv * gg.x + b4.x;
  o.y = (v.y - mu) * inv * gg.y + b4.y;
  o.z = (v.z - mu) * inv * gg.z + b4.z;
  o.w = (v.w - mu) * inv * gg.w + b4.w;
  ((float4*)(y + tE))[tid] = o;
}

// ---------------------------------------------------------------------------
// Kernel 5: W12 GEMM + fused SwiGLU.  Computes column tiles [n0,n0+64) of x1
// and [n0+4096..) of x2 together; writes h = silu(x1)*x2. x12 never hits HBM.
// ---------------------------------------------------------------------------
__global__ __launch_bounds__(256) void k_gemm_w12(
    const float* __restrict__ A, const float* __restrict__ W12,
    const float* __restrict__ b12, float* __restrict__ hbuf)
{
  __shared__ float As[16][132];
  __shared__ float Bs1[16][68];
  __shared__ float Bs2[16][68];
  const int tid = threadIdx.x;
  const int m0 = blockIdx.y * 128;
  const int n0 = blockIdx.x * 64;
  const int tr = tid >> 4;
  const int tc = tid & 15;
  float acc1[8][4] = {};
  float acc2[8][4] = {};

  for (int k0 = 0; k0 < EDIM; k0 += 16) {
    __syncthreads();
#pragma unroll
    for (int u = 0; u < 2; ++u) {
      const int f = tid * 2 + u;
      const int row = f >> 2, kq = f & 3;
      float4 a = *(const float4*)(A + (size_t)(m0 + row) * EDIM + k0 + kq * 4);
      As[kq * 4 + 0][row] = a.x; As[kq * 4 + 1][row] = a.y;
      As[kq * 4 + 2][row] = a.z; As[kq * 4 + 3][row] = a.w;
    }
    {
      const int row = tid >> 2, kq = tid & 3;
      float4 w1 = *(const float4*)(W12 + (size_t)(n0 + row) * EDIM + k0 + kq * 4);
      float4 w2 = *(const float4*)(W12 + (size_t)(FFD + n0 + row) * EDIM + k0 + kq * 4);
      Bs1[kq * 4 + 0][row] = w1.x; Bs1[kq * 4 + 1][row] = w1.y;
      Bs1[kq * 4 + 2][row] = w1.z; Bs1[kq * 4 + 3][row] = w1.w;
      Bs2[kq * 4 + 0][row] = w2.x; Bs2[kq * 4 + 1][row] = w2.y;
      Bs2[kq * 4 + 2][row] = w2.z; Bs2[kq * 4 + 3][row] = w2.w;
    }
    __syncthreads();
#pragma unroll
    for (int kk = 0; kk < 16; ++kk) {
      float4 a0 = *(const float4*)(&As[kk][tr * 8]);
      float4 a1 = *(const float4*)(&As[kk][tr * 8 + 4]);
      float4 b1v = *(const float4*)(&Bs1[kk][tc * 4]);
      float4 b2v = *(const float4*)(&Bs2[kk][tc * 4]);
      const float ar[8] = {a0.x, a0.y, a0.z, a0.w, a1.x, a1.y, a1.z, a1.w};
      const float br1[4] = {b1v.x, b1v.y, b1v.z, b1v.w};
      const float br2[4] = {b2v.x, b2v.y, b2v.z, b2v.w};
#pragma unroll
      for (int ii = 0; ii < 8; ++ii)
#pragma unroll
        for (int jj = 0; jj < 4; ++jj) {
          acc1[ii][jj] = fmaf(ar[ii], br1[jj], acc1[ii][jj]);
          acc2[ii][jj] = fmaf(ar[ii], br2[jj], acc2[ii][jj]);
        }
    }
  }

  const float4 bb1 = *(const float4*)(b12 + n0 + tc * 4);
  const float4 bb2 = *(const float4*)(b12 + FFD + n0 + tc * 4);
  const float bb1a[4] = {bb1.x, bb1.y, bb1.z, bb1.w};
  const float bb2a[4] = {bb2.x, bb2.y, bb2.z, bb2.w};
#pragma unroll
  for (int ii = 0; ii < 8; ++ii) {
    const int row = m0 + tr * 8 + ii;
    float o[4];
#pragma unroll
    for (int jj = 0; jj < 4; ++jj) {
      const float z1 = acc1[ii][jj] + bb1a[jj];
      const float z2 = acc2[ii][jj] + bb2a[jj];
      const float sv = z1 / (1.f + __expf(-z1));   // silu
      o[jj] = sv * z2;
    }
    *(float4*)(hbuf + (size_t)row * FFD + n0 + tc * 4) =
        make_float4(o[0], o[1], o[2], o[3]);
  }
}

// ---------------------------------------------------------------------------
// launch
// ---------------------------------------------------------------------------
extern "C" void kernel_launch(void* const* d_in, const int* in_sizes, int n_in,
                              void* d_out, int out_size, void* d_ws, size_t ws_size,
                              hipStream_t stream)
{
  const float* value = (const float*)d_in[0];
  const float* key   = (const float*)d_in[1];
  const float* query = (const float*)d_in[2];
  const int*   mask  = (const int*)d_in[3];
  const float* g1 = (const float*)d_in[4];
  const float* b1 = (const float*)d_in[5];
  const float* g2 = (const float*)d_in[6];
  const float* b2 = (const float*)d_in[7];
  const float* Wv = (const float*)d_in[8];
  const float* Wk = (const float*)d_in[9];
  const float* Wq = (const float*)d_in[10];
  const float* Wo = (const float*)d_in[11];
  const float* bo = (const float*)d_in[12];
  const float* W12 = (const float*)d_in[13];
  const float* b12 = (const float*)d_in[14];
  const float* W3  = (const float*)d_in[15];
  const float* b3  = (const float*)d_in[16];
  float* out = (float*)d_out;

  float* ws = (float*)d_ws;
  const size_t NE = (size_t)NTOK * EDIM;     // 8M floats
  float* qp = ws;                 // [NTOK, E]
  float* kp = qp + NE;            // [NTOK, E]
  float* vp = kp + NE;            // [NTOK, E]
  float* ao = vp + NE;            // [NTOK, E] attention output (pre-Wo)
  float* hb = ao + NE;            // [NTOK, FF] swiglu hidden
  float* xb = qp;                 // reuse: x = query + attn@Wo.T + bo
  float* xn = kp;                 // reuse: LN2(x)

  // 1) LN1 + QKV head projections
  k_ln_qkv<<<NTOK, 256, 0, stream>>>(query, key, value, g1, b1, Wq, Wk, Wv,
                                     qp, kp, vp);
  // 2) flash attention with ALiBi + mask
  k_attn<<<dim3(SEQ / 64, HN, BATCH), 256, 0, stream>>>(qp, kp, vp, mask, ao);
  // 3) Wo projection + bias + residual(query) -> xb
  k_gemm_nres<<<dim3(EDIM / 128, NTOK / 128), 256, 0, stream>>>(ao, Wo, bo,
                                                                query, xb, EDIM);
  // 4) LN2 -> xn
  k_ln<<<NTOK, 256, 0, stream>>>(xb, g2, b2, xn);
  // 5) W12 + SwiGLU -> hb
  k_gemm_w12<<<dim3(FFD / 64, NTOK / 128), 256, 0, stream>>>(xn, W12, b12, hb);
  // 6) W3 + bias + residual(query) -> out
  k_gemm_nres<<<dim3(EDIM / 128, NTOK / 128), 256, 0, stream>>>(hb, W3, b3,
                                                                query, out, FFD);
}

// Round 3
// 3287.834 us; speedup vs baseline: 2.2530x; 2.2530x over previous
//
#include <hip/hip_runtime.h>
#include <math.h>

#define EDIM 1024
#define HN 16
#define HD 64
#define SEQ 2048
#define BATCH 4
#define FFD 4096
#define NTOK (BATCH*SEQ)

typedef __attribute__((ext_vector_type(8))) short bf16x8;
typedef __attribute__((ext_vector_type(4))) float f32x4;

union BF8 { bf16x8 v; ushort u[8]; };

__device__ __forceinline__ ushort f2bf(float f) {
  unsigned u = __float_as_uint(f);
  u += 0x7FFFu + ((u >> 16) & 1u);      // round-to-nearest-even
  return (ushort)(u >> 16);
}
__device__ __forceinline__ ushort4 f2bf4(float4 f) {
  ushort4 r; r.x = f2bf(f.x); r.y = f2bf(f.y); r.z = f2bf(f.z); r.w = f2bf(f.w);
  return r;
}

// ---------------------------------------------------------------------------
// Kernel 1: fused LayerNorm(g1,b1) of q/k/v rows + per-head 64x64 projection.
// ---------------------------------------------------------------------------
__device__ __forceinline__ void proj_stage(const float* __restrict__ Wg,
                                           const float* xlds, float* wbuf,
                                           float* __restrict__ outp,
                                           size_t tE, int tid)
{
  for (int idx = tid; idx < HD * HD; idx += 256)
    wbuf[(idx >> 6) * 68 + (idx & 63)] = Wg[idx];
  __syncthreads();
  const int i = tid >> 2;
  const int g = tid & 3;
  const float4* wr = (const float4*)(wbuf + i * 68);
#pragma unroll
  for (int hh = 0; hh < 4; ++hh) {
    const int h = g * 4 + hh;
    const float4* xr = (const float4*)(xlds + h * 68);
    float acc = 0.f;
#pragma unroll
    for (int j4 = 0; j4 < 16; ++j4) {
      float4 w = wr[j4], x = xr[j4];
      acc += w.x * x.x + w.y * x.y + w.z * x.z + w.w * x.w;
    }
    outp[tE + h * 64 + i] = acc;
  }
  __syncthreads();
}

__global__ __launch_bounds__(256) void k_ln_qkv(
    const float* __restrict__ qin, const float* __restrict__ kin,
    const float* __restrict__ vin, const float* __restrict__ g1,
    const float* __restrict__ b1, const float* __restrict__ Wq,
    const float* __restrict__ Wk, const float* __restrict__ Wv,
    float* __restrict__ qp, float* __restrict__ kp, float* __restrict__ vp)
{
  __shared__ float xq[HN * 68], xk[HN * 68], xv[HN * 68];
  __shared__ float wbuf[HD * 68];
  __shared__ float red[4][6];
  const int tid = threadIdx.x;
  const size_t tE = (size_t)blockIdx.x * EDIM;

  float4 aq = ((const float4*)(qin + tE))[tid];
  float4 ak = ((const float4*)(kin + tE))[tid];
  float4 av = ((const float4*)(vin + tE))[tid];

  float sq = aq.x + aq.y + aq.z + aq.w;
  float ssq = aq.x * aq.x + aq.y * aq.y + aq.z * aq.z + aq.w * aq.w;
  float sk = ak.x + ak.y + ak.z + ak.w;
  float ssk = ak.x * ak.x + ak.y * ak.y + ak.z * ak.z + ak.w * ak.w;
  float sv = av.x + av.y + av.z + av.w;
  float ssv = av.x * av.x + av.y * av.y + av.z * av.z + av.w * av.w;
#pragma unroll
  for (int off = 32; off; off >>= 1) {
    sq += __shfl_down(sq, off);   ssq += __shfl_down(ssq, off);
    sk += __shfl_down(sk, off);   ssk += __shfl_down(ssk, off);
    sv += __shfl_down(sv, off);   ssv += __shfl_down(ssv, off);
  }
  if ((tid & 63) == 0) {
    const int w = tid >> 6;
    red[w][0] = sq; red[w][1] = ssq; red[w][2] = sk;
    red[w][3] = ssk; red[w][4] = sv; red[w][5] = ssv;
  }
  __syncthreads();
  sq = red[0][0] + red[1][0] + red[2][0] + red[3][0];
  ssq = red[0][1] + red[1][1] + red[2][1] + red[3][1];
  sk = red[0][2] + red[1][2] + red[2][2] + red[3][2];
  ssk = red[0][3] + red[1][3] + red[2][3] + red[3][3];
  sv = red[0][4] + red[1][4] + red[2][4] + red[3][4];
  ssv = red[0][5] + red[1][5] + red[2][5] + red[3][5];

  const float rE = 1.f / EDIM;
  const float muq = sq * rE, muk = sk * rE, muv = sv * rE;
  const float ivq = rsqrtf(ssq * rE - muq * muq + 1e-5f);
  const float ivk = rsqrtf(ssk * rE - muk * muk + 1e-5f);
  const float ivv = rsqrtf(ssv * rE - muv * muv + 1e-5f);

  float4 gg = ((const float4*)g1)[tid];
  float4 bb = ((const float4*)b1)[tid];
  const int j = tid * 4;
  float* dq = xq + (j >> 6) * 68 + (j & 63);
  float* dk = xk + (j >> 6) * 68 + (j & 63);
  float* dv = xv + (j >> 6) * 68 + (j & 63);
  dq[0] = (aq.x - muq) * ivq * gg.x + bb.x;
  dq[1] = (aq.y - muq) * ivq * gg.y + bb.y;
  dq[2] = (aq.z - muq) * ivq * gg.z + bb.z;
  dq[3] = (aq.w - muq) * ivq * gg.w + bb.w;
  dk[0] = (ak.x - muk) * ivk * gg.x + bb.x;
  dk[1] = (ak.y - muk) * ivk * gg.y + bb.y;
  dk[2] = (ak.z - muk) * ivk * gg.z + bb.z;
  dk[3] = (ak.w - muk) * ivk * gg.w + bb.w;
  dv[0] = (av.x - muv) * ivv * gg.x + bb.x;
  dv[1] = (av.y - muv) * ivv * gg.y + bb.y;
  dv[2] = (av.z - muv) * ivv * gg.z + bb.z;
  dv[3] = (av.w - muv) * ivv * gg.w + bb.w;
  __syncthreads();

  proj_stage(Wq, xq, wbuf, qp, tE, tid);
  proj_stage(Wk, xk, wbuf, kp, tE, tid);
  proj_stage(Wv, xv, wbuf, vp, tE, tid);
}

// ---------------------------------------------------------------------------
// Kernel 2: flash attention, bf16 MFMA (16x16x32), fp32 softmax/acc.
// Swapped QK^T: S^T = K·Q^T so C-regs feed PV A-operand with no shuffles.
// Block = 4 waves; wave w owns q rows [qt*64+w*16, +16). KV tile = 64 keys.
// K staged [key][d] bf16 stride 68; V staged transposed [d][key] stride 68.
// ---------------------------------------------------------------------------
__global__ __launch_bounds__(256) void k_attn_mfma(
    const float* __restrict__ qp, const float* __restrict__ kp,
    const float* __restrict__ vp, const int* __restrict__ maskp,
    float* __restrict__ ao)
{
  __shared__ ushort Klds[64 * 68];
  __shared__ ushort Vt[64 * 68];
  __shared__ int Ms[64];
  const int tid = threadIdx.x;
  const int wid = tid >> 6;
  const int lane = tid & 63;
  const int g = lane >> 4;     // 16-lane group 0..3
  const int lq = lane & 15;
  const int qt = blockIdx.x, h = blockIdx.y, b = blockIdx.z;
  const float slope = exp2f(-(float)(h + 1));
  const int q0 = qt * 64 + wid * 16;
  const size_t rowbase = (size_t)b * SEQ;
  const int colh = h * HD;

  // Q B-fragments: 2 d-chunks; elem 0-3 <-> d = c*32+g*4+j, 4-7 <-> +16
  BF8 qf[2];
  {
    const float* qrow = qp + (rowbase + q0 + lq) * EDIM + colh;
#pragma unroll
    for (int c = 0; c < 2; ++c) {
      float4 x = *(const float4*)(qrow + c * 32 + g * 4);
      float4 y = *(const float4*)(qrow + c * 32 + 16 + g * 4);
      qf[c].u[0] = f2bf(x.x); qf[c].u[1] = f2bf(x.y);
      qf[c].u[2] = f2bf(x.z); qf[c].u[3] = f2bf(x.w);
      qf[c].u[4] = f2bf(y.x); qf[c].u[5] = f2bf(y.y);
      qf[c].u[6] = f2bf(y.z); qf[c].u[7] = f2bf(y.w);
    }
  }

  f32x4 O[4];
#pragma unroll
  for (int d = 0; d < 4; ++d) O[d] = (f32x4){0.f, 0.f, 0.f, 0.f};
  float m_run = -1e30f, l_run = 0.f;
  const int qi = q0 + lq;

  for (int kt = 0; kt < SEQ / 64; ++kt) {
    const int kbase = kt * 64;
    __syncthreads();
    // stage K (row-major bf16) and V^T (d-major bf16)
#pragma unroll
    for (int u = 0; u < 4; ++u) {
      const int f = tid + u * 256;
      const int key = f >> 4, c4 = f & 15;
      const size_t grow = (rowbase + kbase + key) * EDIM + colh + c4 * 4;
      float4 kx = *(const float4*)(kp + grow);
      *(ushort4*)(&Klds[key * 68 + c4 * 4]) = f2bf4(kx);
      float4 vx = *(const float4*)(vp + grow);
      Vt[(c4 * 4 + 0) * 68 + key] = f2bf(vx.x);
      Vt[(c4 * 4 + 1) * 68 + key] = f2bf(vx.y);
      Vt[(c4 * 4 + 2) * 68 + key] = f2bf(vx.z);
      Vt[(c4 * 4 + 3) * 68 + key] = f2bf(vx.w);
    }
    if (tid < 64) Ms[tid] = maskp[b * SEQ + kbase + tid];
    __syncthreads();

    // S^T[key][q] = K-tile · Q^T : 4 key-blocks x 2 d-chunks
    f32x4 sT[4];
#pragma unroll
    for (int kb = 0; kb < 4; ++kb) {
      sT[kb] = (f32x4){0.f, 0.f, 0.f, 0.f};
#pragma unroll
      for (int c = 0; c < 2; ++c) {
        BF8 a;
        const ushort* src = &Klds[(kb * 16 + lq) * 68 + c * 32 + g * 4];
        *(ushort4*)(&a.u[0]) = *(const ushort4*)(src);
        *(ushort4*)(&a.u[4]) = *(const ushort4*)(src + 16);
        sT[kb] = __builtin_amdgcn_mfma_f32_16x16x32_bf16(a.v, qf[c].v, sT[kb],
                                                         0, 0, 0);
      }
    }

    // online softmax (per lane: q = q0+lq fixed; 16 keys worth of regs)
    float pv[16];
    float mt = -1e30f;
#pragma unroll
    for (int kb = 0; kb < 4; ++kb)
#pragma unroll
      for (int r = 0; r < 4; ++r) {
        const int kloc = kb * 16 + g * 4 + r;
        const float dist = fabsf((float)(qi - (kbase + kloc)));
        const float s = Ms[kloc] ? (sT[kb][r] - slope * dist) * 0.03125f
                                 : -312.5f;
        pv[kb * 4 + r] = s;
        mt = fmaxf(mt, s);
      }
    mt = fmaxf(mt, __shfl_xor(mt, 16));
    mt = fmaxf(mt, __shfl_xor(mt, 32));
    const float mn = fmaxf(m_run, mt);
    const float corr = __expf(m_run - mn);
    m_run = mn;

    float sum = 0.f;
    BF8 pa[2];
#pragma unroll
    for (int idx = 0; idx < 16; ++idx) {
      const float p = __expf(pv[idx] - mn);
      sum += p;
      pa[idx >> 3].u[idx & 7] = f2bf(p);
    }
    sum += __shfl_xor(sum, 16);
    sum += __shfl_xor(sum, 32);
    l_run = l_run * corr + sum;

    // rescale O: O rows are q = g*4+r -> fetch corr from lane (g*4+r)
    float corrO[4];
#pragma unroll
    for (int r = 0; r < 4; ++r) corrO[r] = __shfl(corr, g * 4 + r);
#pragma unroll
    for (int d = 0; d < 4; ++d)
#pragma unroll
      for (int r = 0; r < 4; ++r) O[d][r] *= corrO[r];

    // PV: O[q][d] += P · V ; B-frags from V^T rows (plain b64 reads)
#pragma unroll
    for (int d = 0; d < 4; ++d) {
#pragma unroll
      for (int c = 0; c < 2; ++c) {
        BF8 vb;
        const ushort* vsrc = &Vt[(d * 16 + lq) * 68 + c * 32 + g * 4];
        *(ushort4*)(&vb.u[0]) = *(const ushort4*)(vsrc);
        *(ushort4*)(&vb.u[4]) = *(const ushort4*)(vsrc + 16);
        O[d] = __builtin_amdgcn_mfma_f32_16x16x32_bf16(pa[c].v, vb.v, O[d],
                                                       0, 0, 0);
      }
    }
  }

  // epilogue: normalize by row-sum and store fp32
  float linv[4];
#pragma unroll
  for (int r = 0; r < 4; ++r) linv[r] = 1.f / __shfl(l_run, g * 4 + r);
#pragma unroll
  for (int d = 0; d < 4; ++d)
#pragma unroll
    for (int r = 0; r < 4; ++r)
      ao[(rowbase + q0 + g * 4 + r) * EDIM + colh + d * 16 + lq] =
          O[d][r] * linv[r];
}

// ---------------------------------------------------------------------------
// Kernel 3: fp32 GEMM  out[M,1024] = A[M,K] @ W[1024,K]^T + bias + resid.
// Tile 128x128, K-step 16, 8x8 per thread.
// ---------------------------------------------------------------------------
__global__ __launch_bounds__(256) void k_gemm_nres(
    const float* __restrict__ A, const float* __restrict__ W,
    const float* __restrict__ bias, const float* __restrict__ resid,
    float* __restrict__ out, int K)
{
  __shared__ float As[16][132];
  __shared__ float Bs[16][132];
  const int tid = threadIdx.x;
  const int m0 = blockIdx.y * 128;
  const int n0 = blockIdx.x * 128;
  const int tr = tid >> 4;
  const int tc = tid & 15;
  float acc[8][8] = {};

  for (int k0 = 0; k0 < K; k0 += 16) {
    __syncthreads();
#pragma unroll
    for (int u = 0; u < 2; ++u) {
      const int f = tid * 2 + u;
      const int row = f >> 2, kq = f & 3;
      float4 a = *(const float4*)(A + (size_t)(m0 + row) * K + k0 + kq * 4);
      As[kq * 4 + 0][row] = a.x; As[kq * 4 + 1][row] = a.y;
      As[kq * 4 + 2][row] = a.z; As[kq * 4 + 3][row] = a.w;
      float4 bv = *(const float4*)(W + (size_t)(n0 + row) * K + k0 + kq * 4);
      Bs[kq * 4 + 0][row] = bv.x; Bs[kq * 4 + 1][row] = bv.y;
      Bs[kq * 4 + 2][row] = bv.z; Bs[kq * 4 + 3][row] = bv.w;
    }
    __syncthreads();
#pragma unroll
    for (int kk = 0; kk < 16; ++kk) {
      float4 a0 = *(const float4*)(&As[kk][tr * 8]);
      float4 a1 = *(const float4*)(&As[kk][tr * 8 + 4]);
      float4 b0 = *(const float4*)(&Bs[kk][tc * 8]);
      float4 b1 = *(const float4*)(&Bs[kk][tc * 8 + 4]);
      const float ar[8] = {a0.x, a0.y, a0.z, a0.w, a1.x, a1.y, a1.z, a1.w};
      const float br[8] = {b0.x, b0.y, b0.z, b0.w, b1.x, b1.y, b1.z, b1.w};
#pragma unroll
      for (int ii = 0; ii < 8; ++ii)
#pragma unroll
        for (int jj = 0; jj < 8; ++jj)
          acc[ii][jj] = fmaf(ar[ii], br[jj], acc[ii][jj]);
    }
  }

  const float4 bva = *(const float4*)(bias + n0 + tc * 8);
  const float4 bvb = *(const float4*)(bias + n0 + tc * 8 + 4);
#pragma unroll
  for (int ii = 0; ii < 8; ++ii) {
    const int row = m0 + tr * 8 + ii;
    const float4 r0 = *(const float4*)(resid + (size_t)row * EDIM + n0 + tc * 8);
    const float4 r1 = *(const float4*)(resid + (size_t)row * EDIM + n0 + tc * 8 + 4);
    float4 o0, o1;
    o0.x = acc[ii][0] + bva.x + r0.x;
    o0.y = acc[ii][1] + bva.y + r0.y;
    o0.z = acc[ii][2] + bva.z + r0.z;
    o0.w = acc[ii][3] + bva.w + r0.w;
    o1.x = acc[ii][4] + bvb.x + r1.x;
    o1.y = acc[ii][5] + bvb.y + r1.y;
    o1.z = acc[ii][6] + bvb.z + r1.z;
    o1.w = acc[ii][7] + bvb.w + r1.w;
    *(float4*)(out + (size_t)row * EDIM + n0 + tc * 8) = o0;
    *(float4*)(out + (size_t)row * EDIM + n0 + tc * 8 + 4) = o1;
  }
}

// ---------------------------------------------------------------------------
// Kernel 4: LayerNorm (one block per token)
// ---------------------------------------------------------------------------
__global__ __launch_bounds__(256) void k_ln(
    const float* __restrict__ x, const float* __restrict__ g,
    const float* __restrict__ bb, float* __restrict__ y)
{
  __shared__ float red[4][2];
  const int tid = threadIdx.x;
  const size_t tE = (size_t)blockIdx.x * EDIM;
  float4 v = ((const float4*)(x + tE))[tid];
  float s = v.x + v.y + v.z + v.w;
  float ss = v.x * v.x + v.y * v.y + v.z * v.z + v.w * v.w;
#pragma unroll
  for (int off = 32; off; off >>= 1) {
    s += __shfl_down(s, off); ss += __shfl_down(ss, off);
  }
  if ((tid & 63) == 0) { red[tid >> 6][0] = s; red[tid >> 6][1] = ss; }
  __syncthreads();
  s = red[0][0] + red[1][0] + red[2][0] + red[3][0];
  ss = red[0][1] + red[1][1] + red[2][1] + red[3][1];
  const float mu = s * (1.f / EDIM);
  const float inv = rsqrtf(ss * (1.f / EDIM) - mu * mu + 1e-5f);
  float4 gg = ((const float4*)g)[tid];
  float4 b4 = ((const float4*)bb)[tid];
  float4 o;
  o.x = (v.x - mu) * inv * gg.x + b4.x;
  o.y = (v.y - mu) * inv * gg.y + b4.y;
  o.z = (v.z - mu) * inv * gg.z + b4.z;
  o.w = (v.w - mu) * inv * gg.w + b4.w;
  ((float4*)(y + tE))[tid] = o;
}

// ---------------------------------------------------------------------------
// Kernel 5: W12 GEMM + fused SwiGLU.
// ---------------------------------------------------------------------------
__global__ __launch_bounds__(256) void k_gemm_w12(
    const float* __restrict__ A, const float* __restrict__ W12,
    const float* __restrict__ b12, float* __restrict__ hbuf)
{
  __shared__ float As[16][132];
  __shared__ float Bs1[16][68];
  __shared__ float Bs2[16][68];
  const int tid = threadIdx.x;
  const int m0 = blockIdx.y * 128;
  const int n0 = blockIdx.x * 64;
  const int tr = tid >> 4;
  const int tc = tid & 15;
  float acc1[8][4] = {};
  float acc2[8][4] = {};

  for (int k0 = 0; k0 < EDIM; k0 += 16) {
    __syncthreads();
#pragma unroll
    for (int u = 0; u < 2; ++u) {
      const int f = tid * 2 + u;
      const int row = f >> 2, kq = f & 3;
      float4 a = *(const float4*)(A + (size_t)(m0 + row) * EDIM + k0 + kq * 4);
      As[kq * 4 + 0][row] = a.x; As[kq * 4 + 1][row] = a.y;
      As[kq * 4 + 2][row] = a.z; As[kq * 4 + 3][row] = a.w;
    }
    {
      const int row = tid >> 2, kq = tid & 3;
      float4 w1 = *(const float4*)(W12 + (size_t)(n0 + row) * EDIM + k0 + kq * 4);
      float4 w2 = *(const float4*)(W12 + (size_t)(FFD + n0 + row) * EDIM + k0 + kq * 4);
      Bs1[kq * 4 + 0][row] = w1.x; Bs1[kq * 4 + 1][row] = w1.y;
      Bs1[kq * 4 + 2][row] = w1.z; Bs1[kq * 4 + 3][row] = w1.w;
      Bs2[kq * 4 + 0][row] = w2.x; Bs2[kq * 4 + 1][row] = w2.y;
      Bs2[kq * 4 + 2][row] = w2.z; Bs2[kq * 4 + 3][row] = w2.w;
    }
    __syncthreads();
#pragma unroll
    for (int kk = 0; kk < 16; ++kk) {
      float4 a0 = *(const float4*)(&As[kk][tr * 8]);
      float4 a1 = *(const float4*)(&As[kk][tr * 8 + 4]);
      float4 b1v = *(const float4*)(&Bs1[kk][tc * 4]);
      float4 b2v = *(const float4*)(&Bs2[kk][tc * 4]);
      const float ar[8] = {a0.x, a0.y, a0.z, a0.w, a1.x, a1.y, a1.z, a1.w};
      const float br1[4] = {b1v.x, b1v.y, b1v.z, b1v.w};
      const float br2[4] = {b2v.x, b2v.y, b2v.z, b2v.w};
#pragma unroll
      for (int ii = 0; ii < 8; ++ii)
#pragma unroll
        for (int jj = 0; jj < 4; ++jj) {
          acc1[ii][jj] = fmaf(ar[ii], br1[jj], acc1[ii][jj]);
          acc2[ii][jj] = fmaf(ar[ii], br2[jj], acc2[ii][jj]);
        }
    }
  }

  const float4 bb1 = *(const float4*)(b12 + n0 + tc * 4);
  const float4 bb2 = *(const float4*)(b12 + FFD + n0 + tc * 4);
  const float bb1a[4] = {bb1.x, bb1.y, bb1.z, bb1.w};
  const float bb2a[4] = {bb2.x, bb2.y, bb2.z, bb2.w};
#pragma unroll
  for (int ii = 0; ii < 8; ++ii) {
    const int row = m0 + tr * 8 + ii;
    float o[4];
#pragma unroll
    for (int jj = 0; jj < 4; ++jj) {
      const float z1 = acc1[ii][jj] + bb1a[jj];
      const float z2 = acc2[ii][jj] + bb2a[jj];
      const float sv = z1 / (1.f + __expf(-z1));
      o[jj] = sv * z2;
    }
    *(float4*)(hbuf + (size_t)row * FFD + n0 + tc * 4) =
        make_float4(o[0], o[1], o[2], o[3]);
  }
}

// ---------------------------------------------------------------------------
// launch
// ---------------------------------------------------------------------------
extern "C" void kernel_launch(void* const* d_in, const int* in_sizes, int n_in,
                              void* d_out, int out_size, void* d_ws, size_t ws_size,
                              hipStream_t stream)
{
  const float* value = (const float*)d_in[0];
  const float* key   = (const float*)d_in[1];
  const float* query = (const float*)d_in[2];
  const int*   mask  = (const int*)d_in[3];
  const float* g1 = (const float*)d_in[4];
  const float* b1 = (const float*)d_in[5];
  const float* g2 = (const float*)d_in[6];
  const float* b2 = (const float*)d_in[7];
  const float* Wv = (const float*)d_in[8];
  const float* Wk = (const float*)d_in[9];
  const float* Wq = (const float*)d_in[10];
  const float* Wo = (const float*)d_in[11];
  const float* bo = (const float*)d_in[12];
  const float* W12 = (const float*)d_in[13];
  const float* b12 = (const float*)d_in[14];
  const float* W3  = (const float*)d_in[15];
  const float* b3  = (const float*)d_in[16];
  float* out = (float*)d_out;

  float* ws = (float*)d_ws;
  const size_t NE = (size_t)NTOK * EDIM;
  float* qp = ws;
  float* kp = qp + NE;
  float* vp = kp + NE;
  float* ao = vp + NE;
  float* hb = ao + NE;
  float* xb = qp;
  float* xn = kp;

  k_ln_qkv<<<NTOK, 256, 0, stream>>>(query, key, value, g1, b1, Wq, Wk, Wv,
                                     qp, kp, vp);
  k_attn_mfma<<<dim3(SEQ / 64, HN, BATCH), 256, 0, stream>>>(qp, kp, vp, mask,
                                                             ao);
  k_gemm_nres<<<dim3(EDIM / 128, NTOK / 128), 256, 0, stream>>>(ao, Wo, bo,
                                                                query, xb, EDIM);
  k_ln<<<NTOK, 256, 0, stream>>>(xb, g2, b2, xn);
  k_gemm_w12<<<dim3(FFD / 64, NTOK / 128), 256, 0, stream>>>(xn, W12, b12, hb);
  k_gemm_nres<<<dim3(EDIM / 128, NTOK / 128), 256, 0, stream>>>(hb, W3, b3,
                                                                query, out, FFD);
}

// Round 6
// 927.622 us; speedup vs baseline: 7.9856x; 3.5444x over previous
//
#include <hip/hip_runtime.h>
#include <math.h>

#define EDIM 1024
#define HN 16
#define HD 64
#define SEQ 2048
#define BATCH 4
#define FFD 4096
#define NTOK (BATCH*SEQ)

typedef __attribute__((ext_vector_type(8))) short bf16x8;
typedef __attribute__((ext_vector_type(4))) float f32x4;

union BF8 { bf16x8 v; ushort u[8]; };

__device__ __forceinline__ ushort f2bf(float f) {
  unsigned u = __float_as_uint(f);
  u += 0x7FFFu + ((u >> 16) & 1u);      // round-to-nearest-even
  return (ushort)(u >> 16);
}

// ---------------------------------------------------------------------------
// Kernel 0: fp32 -> bf16 bulk convert (weights), n4 = elements/4
// ---------------------------------------------------------------------------
__global__ __launch_bounds__(256) void k_f2b(const float* __restrict__ s,
                                             ushort* __restrict__ d, int n4)
{
  const int i = blockIdx.x * 256 + threadIdx.x;
  if (i < n4) {
    float4 v = ((const float4*)s)[i];
    ushort4 o; o.x = f2bf(v.x); o.y = f2bf(v.y); o.z = f2bf(v.z); o.w = f2bf(v.w);
    ((ushort4*)d)[i] = o;
  }
}

// ---------------------------------------------------------------------------
// Kernel 1: fused LayerNorm(g1,b1) of q/k/v rows + per-head 64x64 projection.
// Outputs bf16 (consumed by MFMA attention).
// ---------------------------------------------------------------------------
__device__ __forceinline__ void proj_stage(const float* __restrict__ Wg,
                                           const float* xlds, float* wbuf,
                                           ushort* __restrict__ outp,
                                           size_t tE, int tid)
{
  for (int idx = tid; idx < HD * HD; idx += 256)
    wbuf[(idx >> 6) * 68 + (idx & 63)] = Wg[idx];
  __syncthreads();
  const int i = tid >> 2;
  const int g = tid & 3;
  const float4* wr = (const float4*)(wbuf + i * 68);
#pragma unroll
  for (int hh = 0; hh < 4; ++hh) {
    const int h = g * 4 + hh;
    const float4* xr = (const float4*)(xlds + h * 68);
    float acc = 0.f;
#pragma unroll
    for (int j4 = 0; j4 < 16; ++j4) {
      float4 w = wr[j4], x = xr[j4];
      acc += w.x * x.x + w.y * x.y + w.z * x.z + w.w * x.w;
    }
    outp[tE + h * 64 + i] = f2bf(acc);
  }
  __syncthreads();
}

__global__ __launch_bounds__(256) void k_ln_qkv(
    const float* __restrict__ qin, const float* __restrict__ kin,
    const float* __restrict__ vin, const float* __restrict__ g1,
    const float* __restrict__ b1, const float* __restrict__ Wq,
    const float* __restrict__ Wk, const float* __restrict__ Wv,
    ushort* __restrict__ qp, ushort* __restrict__ kp, ushort* __restrict__ vp)
{
  __shared__ float xq[HN * 68], xk[HN * 68], xv[HN * 68];
  __shared__ float wbuf[HD * 68];
  __shared__ float red[4][6];
  const int tid = threadIdx.x;
  const size_t tE = (size_t)blockIdx.x * EDIM;

  float4 aq = ((const float4*)(qin + tE))[tid];
  float4 ak = ((const float4*)(kin + tE))[tid];
  float4 av = ((const float4*)(vin + tE))[tid];

  float sq = aq.x + aq.y + aq.z + aq.w;
  float ssq = aq.x * aq.x + aq.y * aq.y + aq.z * aq.z + aq.w * aq.w;
  float sk = ak.x + ak.y + ak.z + ak.w;
  float ssk = ak.x * ak.x + ak.y * ak.y + ak.z * ak.z + ak.w * ak.w;
  float sv = av.x + av.y + av.z + av.w;
  float ssv = av.x * av.x + av.y * av.y + av.z * av.z + av.w * av.w;
#pragma unroll
  for (int off = 32; off; off >>= 1) {
    sq += __shfl_down(sq, off);   ssq += __shfl_down(ssq, off);
    sk += __shfl_down(sk, off);   ssk += __shfl_down(ssk, off);
    sv += __shfl_down(sv, off);   ssv += __shfl_down(ssv, off);
  }
  if ((tid & 63) == 0) {
    const int w = tid >> 6;
    red[w][0] = sq; red[w][1] = ssq; red[w][2] = sk;
    red[w][3] = ssk; red[w][4] = sv; red[w][5] = ssv;
  }
  __syncthreads();
  sq = red[0][0] + red[1][0] + red[2][0] + red[3][0];
  ssq = red[0][1] + red[1][1] + red[2][1] + red[3][1];
  sk = red[0][2] + red[1][2] + red[2][2] + red[3][2];
  ssk = red[0][3] + red[1][3] + red[2][3] + red[3][3];
  sv = red[0][4] + red[1][4] + red[2][4] + red[3][4];
  ssv = red[0][5] + red[1][5] + red[2][5] + red[3][5];

  const float rE = 1.f / EDIM;
  const float muq = sq * rE, muk = sk * rE, muv = sv * rE;
  const float ivq = rsqrtf(ssq * rE - muq * muq + 1e-5f);
  const float ivk = rsqrtf(ssk * rE - muk * muk + 1e-5f);
  const float ivv = rsqrtf(ssv * rE - muv * muv + 1e-5f);

  float4 gg = ((const float4*)g1)[tid];
  float4 bb = ((const float4*)b1)[tid];
  const int j = tid * 4;
  float* dq = xq + (j >> 6) * 68 + (j & 63);
  float* dk = xk + (j >> 6) * 68 + (j & 63);
  float* dv = xv + (j >> 6) * 68 + (j & 63);
  dq[0] = (aq.x - muq) * ivq * gg.x + bb.x;
  dq[1] = (aq.y - muq) * ivq * gg.y + bb.y;
  dq[2] = (aq.z - muq) * ivq * gg.z + bb.z;
  dq[3] = (aq.w - muq) * ivq * gg.w + bb.w;
  dk[0] = (ak.x - muk) * ivk * gg.x + bb.x;
  dk[1] = (ak.y - muk) * ivk * gg.y + bb.y;
  dk[2] = (ak.z - muk) * ivk * gg.z + bb.z;
  dk[3] = (ak.w - muk) * ivk * gg.w + bb.w;
  dv[0] = (av.x - muv) * ivv * gg.x + bb.x;
  dv[1] = (av.y - muv) * ivv * gg.y + bb.y;
  dv[2] = (av.z - muv) * ivv * gg.z + bb.z;
  dv[3] = (av.w - muv) * ivv * gg.w + bb.w;
  __syncthreads();

  proj_stage(Wq, xq, wbuf, qp, tE, tid);
  proj_stage(Wk, xk, wbuf, kp, tE, tid);
  proj_stage(Wv, xv, wbuf, vp, tE, tid);
}

// ---------------------------------------------------------------------------
// Kernel 2: flash attention, bf16 in (qp/kp/vp), bf16 out (aob).
// Swapped QK^T (S^T = K.Q^T) so C-regs feed PV A-operand directly.
// K staged [key][d] stride 76; V staged transposed [d][key] stride 76.
// ---------------------------------------------------------------------------
__global__ __launch_bounds__(256) void k_attn_mfma(
    const ushort* __restrict__ qp, const ushort* __restrict__ kp,
    const ushort* __restrict__ vp, const int* __restrict__ maskp,
    ushort* __restrict__ aob)
{
  __shared__ ushort Klds[64 * 76];
  __shared__ ushort Vt[64 * 76];
  __shared__ int Ms[64];
  const int tid = threadIdx.x;
  const int wid = tid >> 6;
  const int lane = tid & 63;
  const int g = lane >> 4;
  const int lq = lane & 15;
  const int qt = blockIdx.x, h = blockIdx.y, b = blockIdx.z;
  const float slope = exp2f(-(float)(h + 1));
  const int q0 = qt * 64 + wid * 16;
  const size_t rowbase = (size_t)b * SEQ;
  const int colh = h * HD;

  BF8 qf[2];
  {
    const ushort* qrow = qp + (rowbase + q0 + lq) * EDIM + colh;
#pragma unroll
    for (int c = 0; c < 2; ++c) {
      *(ushort4*)(&qf[c].u[0]) = *(const ushort4*)(qrow + c * 32 + g * 4);
      *(ushort4*)(&qf[c].u[4]) = *(const ushort4*)(qrow + c * 32 + 16 + g * 4);
    }
  }

  f32x4 O[4];
#pragma unroll
  for (int d = 0; d < 4; ++d) O[d] = (f32x4){0.f, 0.f, 0.f, 0.f};
  float m_run = -1e30f, l_run = 0.f;
  const int qi = q0 + lq;

  for (int kt = 0; kt < SEQ / 64; ++kt) {
    const int kbase = kt * 64;
    __syncthreads();
#pragma unroll
    for (int u = 0; u < 2; ++u) {
      const int f = tid + u * 256;          // 512 chunks of 8 bf16
      const int key = f >> 3, c8 = f & 7;
      const ushort* ks = kp + (rowbase + kbase + key) * EDIM + colh + c8 * 8;
      ushort4 k0v = *(const ushort4*)ks;
      ushort4 k1v = *(const ushort4*)(ks + 4);
      *(ushort4*)(&Klds[key * 76 + c8 * 8]) = k0v;
      *(ushort4*)(&Klds[key * 76 + c8 * 8 + 4]) = k1v;
      const ushort* vs = vp + (rowbase + kbase + key) * EDIM + colh + c8 * 8;
      ushort4 v0 = *(const ushort4*)vs;
      ushort4 v1 = *(const ushort4*)(vs + 4);
      Vt[(c8 * 8 + 0) * 76 + key] = v0.x;
      Vt[(c8 * 8 + 1) * 76 + key] = v0.y;
      Vt[(c8 * 8 + 2) * 76 + key] = v0.z;
      Vt[(c8 * 8 + 3) * 76 + key] = v0.w;
      Vt[(c8 * 8 + 4) * 76 + key] = v1.x;
      Vt[(c8 * 8 + 5) * 76 + key] = v1.y;
      Vt[(c8 * 8 + 6) * 76 + key] = v1.z;
      Vt[(c8 * 8 + 7) * 76 + key] = v1.w;
    }
    if (tid < 64) Ms[tid] = maskp[b * SEQ + kbase + tid];
    __syncthreads();

    f32x4 sT[4];
#pragma unroll
    for (int kb = 0; kb < 4; ++kb) {
      sT[kb] = (f32x4){0.f, 0.f, 0.f, 0.f};
#pragma unroll
      for (int c = 0; c < 2; ++c) {
        BF8 a;
        const ushort* src = &Klds[(kb * 16 + lq) * 76 + c * 32 + g * 4];
        *(ushort4*)(&a.u[0]) = *(const ushort4*)(src);
        *(ushort4*)(&a.u[4]) = *(const ushort4*)(src + 16);
        sT[kb] = __builtin_amdgcn_mfma_f32_16x16x32_bf16(a.v, qf[c].v, sT[kb],
                                                         0, 0, 0);
      }
    }

    float pv[16];
    float mt = -1e30f;
#pragma unroll
    for (int kb = 0; kb < 4; ++kb)
#pragma unroll
      for (int r = 0; r < 4; ++r) {
        const int kloc = kb * 16 + g * 4 + r;
        const float dist = fabsf((float)(qi - (kbase + kloc)));
        const float s = Ms[kloc] ? (sT[kb][r] - slope * dist) * 0.03125f
                                 : -312.5f;
        pv[kb * 4 + r] = s;
        mt = fmaxf(mt, s);
      }
    mt = fmaxf(mt, __shfl_xor(mt, 16));
    mt = fmaxf(mt, __shfl_xor(mt, 32));
    const float mn = fmaxf(m_run, mt);
    const float corr = __expf(m_run - mn);
    m_run = mn;

    float sum = 0.f;
    BF8 pa[2];
#pragma unroll
    for (int idx = 0; idx < 16; ++idx) {
      const float p = __expf(pv[idx] - mn);
      sum += p;
      pa[idx >> 3].u[idx & 7] = f2bf(p);
    }
    sum += __shfl_xor(sum, 16);
    sum += __shfl_xor(sum, 32);
    l_run = l_run * corr + sum;

    float corrO[4];
#pragma unroll
    for (int r = 0; r < 4; ++r) corrO[r] = __shfl(corr, g * 4 + r);
#pragma unroll
    for (int d = 0; d < 4; ++d)
#pragma unroll
      for (int r = 0; r < 4; ++r) O[d][r] *= corrO[r];

#pragma unroll
    for (int d = 0; d < 4; ++d) {
#pragma unroll
      for (int c = 0; c < 2; ++c) {
        BF8 vb;
        const ushort* vsrc = &Vt[(d * 16 + lq) * 76 + c * 32 + g * 4];
        *(ushort4*)(&vb.u[0]) = *(const ushort4*)(vsrc);
        *(ushort4*)(&vb.u[4]) = *(const ushort4*)(vsrc + 16);
        O[d] = __builtin_amdgcn_mfma_f32_16x16x32_bf16(pa[c].v, vb.v, O[d],
                                                       0, 0, 0);
      }
    }
  }

  float linv[4];
#pragma unroll
  for (int r = 0; r < 4; ++r) linv[r] = 1.f / __shfl(l_run, g * 4 + r);
#pragma unroll
  for (int d = 0; d < 4; ++d)
#pragma unroll
    for (int r = 0; r < 4; ++r)
      aob[(rowbase + q0 + g * 4 + r) * EDIM + colh + d * 16 + lq] =
          f2bf(O[d][r] * linv[r]);
}

// ---------------------------------------------------------------------------
// Kernel 3: bf16 MFMA GEMM  out[M,1024] = A[M,K]·W[1024,K]^T + bias + resid.
// 128x128 tile, BK=32, 4 waves (2x2 of 64x64), 16 MFMA : 16 ds_read_b64.
// LDS stride 36 shorts (pad) -> ~2-way bank aliasing (free).
// ---------------------------------------------------------------------------
__global__ __launch_bounds__(256) void k_gemm_bf(
    const ushort* __restrict__ A, const ushort* __restrict__ W,
    const float* __restrict__ bias, const float* __restrict__ resid,
    float* __restrict__ out, int K)
{
  __shared__ ushort As[128 * 36];
  __shared__ ushort Bs[128 * 36];
  const int tid = threadIdx.x;
  const int wid = tid >> 6, lane = tid & 63;
  const int g = lane >> 4, lq = lane & 15;
  const int m0 = blockIdx.y * 128, n0 = blockIdx.x * 128;
  const int wr = wid >> 1, wc = wid & 1;

  f32x4 acc[4][4];
#pragma unroll
  for (int mi = 0; mi < 4; ++mi)
#pragma unroll
    for (int ni = 0; ni < 4; ++ni) acc[mi][ni] = (f32x4){0.f, 0.f, 0.f, 0.f};

  for (int k0 = 0; k0 < K; k0 += 32) {
    __syncthreads();
#pragma unroll
    for (int u = 0; u < 2; ++u) {
      const int c = tid + u * 256;        // 512 chunks of 8 bf16 per tile
      const int row = c >> 2, kc = c & 3;
      uint4 av = *(const uint4*)(A + (size_t)(m0 + row) * K + k0 + kc * 8);
      ushort* da = As + row * 36 + kc * 8;
      *(uint2*)(da) = make_uint2(av.x, av.y);
      *(uint2*)(da + 4) = make_uint2(av.z, av.w);
      uint4 bv = *(const uint4*)(W + (size_t)(n0 + row) * K + k0 + kc * 8);
      ushort* db = Bs + row * 36 + kc * 8;
      *(uint2*)(db) = make_uint2(bv.x, bv.y);
      *(uint2*)(db + 4) = make_uint2(bv.z, bv.w);
    }
    __syncthreads();

    BF8 af[4], bf[4];
#pragma unroll
    for (int i = 0; i < 4; ++i) {
      const ushort* pa = As + (wr * 64 + i * 16 + lq) * 36 + g * 4;
      *(ushort4*)(&af[i].u[0]) = *(const ushort4*)(pa);
      *(ushort4*)(&af[i].u[4]) = *(const ushort4*)(pa + 16);
      const ushort* pb = Bs + (wc * 64 + i * 16 + lq) * 36 + g * 4;
      *(ushort4*)(&bf[i].u[0]) = *(const ushort4*)(pb);
      *(ushort4*)(&bf[i].u[4]) = *(const ushort4*)(pb + 16);
    }
#pragma unroll
    for (int mi = 0; mi < 4; ++mi)
#pragma unroll
      for (int ni = 0; ni < 4; ++ni)
        acc[mi][ni] = __builtin_amdgcn_mfma_f32_16x16x32_bf16(
            af[mi].v, bf[ni].v, acc[mi][ni], 0, 0, 0);
  }

#pragma unroll
  for (int mi = 0; mi < 4; ++mi)
#pragma unroll
    for (int ni = 0; ni < 4; ++ni) {
      const int n = n0 + wc * 64 + ni * 16 + lq;
      const float bv = bias[n];
#pragma unroll
      for (int r = 0; r < 4; ++r) {
        const int m = m0 + wr * 64 + mi * 16 + g * 4 + r;
        out[(size_t)m * EDIM + n] =
            acc[mi][ni][r] + bv + resid[(size_t)m * EDIM + n];
      }
    }
}

// ---------------------------------------------------------------------------
// Kernel 4: LayerNorm, fp32 in -> bf16 out (one block per token)
// ---------------------------------------------------------------------------
__global__ __launch_bounds__(256) void k_ln(
    const float* __restrict__ x, const float* __restrict__ g,
    const float* __restrict__ bb, ushort* __restrict__ y)
{
  __shared__ float red[4][2];
  const int tid = threadIdx.x;
  const size_t tE = (size_t)blockIdx.x * EDIM;
  float4 v = ((const float4*)(x + tE))[tid];
  float s = v.x + v.y + v.z + v.w;
  float ss = v.x * v.x + v.y * v.y + v.z * v.z + v.w * v.w;
#pragma unroll
  for (int off = 32; off; off >>= 1) {
    s += __shfl_down(s, off); ss += __shfl_down(ss, off);
  }
  if ((tid & 63) == 0) { red[tid >> 6][0] = s; red[tid >> 6][1] = ss; }
  __syncthreads();
  s = red[0][0] + red[1][0] + red[2][0] + red[3][0];
  ss = red[0][1] + red[1][1] + red[2][1] + red[3][1];
  const float mu = s * (1.f / EDIM);
  const float inv = rsqrtf(ss * (1.f / EDIM) - mu * mu + 1e-5f);
  float4 gg = ((const float4*)g)[tid];
  float4 b4 = ((const float4*)bb)[tid];
  ushort4 o;
  o.x = f2bf((v.x - mu) * inv * gg.x + b4.x);
  o.y = f2bf((v.y - mu) * inv * gg.y + b4.y);
  o.z = f2bf((v.z - mu) * inv * gg.z + b4.z);
  o.w = f2bf((v.w - mu) * inv * gg.w + b4.w);
  *(ushort4*)(y + tE + tid * 4) = o;
}

// ---------------------------------------------------------------------------
// Kernel 5: W12 bf16 MFMA GEMM + fused SwiGLU -> bf16 hidden.
// Tile 128m x (64 x1-cols + 64 x2-cols), BK=32, 4 waves (2x2 of 64x32 x2).
// ---------------------------------------------------------------------------
__global__ __launch_bounds__(256) void k_gemm_w12sw(
    const ushort* __restrict__ A, const ushort* __restrict__ W12,
    const float* __restrict__ b12, ushort* __restrict__ hbb)
{
  __shared__ ushort As[128 * 36];
  __shared__ ushort Bs1[64 * 36];
  __shared__ ushort Bs2[64 * 36];
  const int tid = threadIdx.x;
  const int wid = tid >> 6, lane = tid & 63;
  const int g = lane >> 4, lq = lane & 15;
  const int m0 = blockIdx.y * 128, n0 = blockIdx.x * 64;
  const int wr = wid >> 1, wc = wid & 1;

  f32x4 acc1[4][2], acc2[4][2];
#pragma unroll
  for (int mi = 0; mi < 4; ++mi)
#pragma unroll
    for (int ni = 0; ni < 2; ++ni) {
      acc1[mi][ni] = (f32x4){0.f, 0.f, 0.f, 0.f};
      acc2[mi][ni] = (f32x4){0.f, 0.f, 0.f, 0.f};
    }

  for (int k0 = 0; k0 < EDIM; k0 += 32) {
    __syncthreads();
#pragma unroll
    for (int u = 0; u < 2; ++u) {
      const int c = tid + u * 256;
      const int row = c >> 2, kc = c & 3;
      uint4 av = *(const uint4*)(A + (size_t)(m0 + row) * EDIM + k0 + kc * 8);
      ushort* da = As + row * 36 + kc * 8;
      *(uint2*)(da) = make_uint2(av.x, av.y);
      *(uint2*)(da + 4) = make_uint2(av.z, av.w);
    }
    {
      const int row = tid >> 2, kc = tid & 3;
      uint4 b1 = *(const uint4*)(W12 + (size_t)(n0 + row) * EDIM + k0 + kc * 8);
      ushort* d1 = Bs1 + row * 36 + kc * 8;
      *(uint2*)(d1) = make_uint2(b1.x, b1.y);
      *(uint2*)(d1 + 4) = make_uint2(b1.z, b1.w);
      uint4 b2 = *(const uint4*)(W12 + (size_t)(FFD + n0 + row) * EDIM + k0 + kc * 8);
      ushort* d2 = Bs2 + row * 36 + kc * 8;
      *(uint2*)(d2) = make_uint2(b2.x, b2.y);
      *(uint2*)(d2 + 4) = make_uint2(b2.z, b2.w);
    }
    __syncthreads();

    BF8 af[4], bf1[2], bf2[2];
#pragma unroll
    for (int i = 0; i < 4; ++i) {
      const ushort* pa = As + (wr * 64 + i * 16 + lq) * 36 + g * 4;
      *(ushort4*)(&af[i].u[0]) = *(const ushort4*)(pa);
      *(ushort4*)(&af[i].u[4]) = *(const ushort4*)(pa + 16);
    }
#pragma unroll
    for (int i = 0; i < 2; ++i) {
      const ushort* p1 = Bs1 + (wc * 32 + i * 16 + lq) * 36 + g * 4;
      *(ushort4*)(&bf1[i].u[0]) = *(const ushort4*)(p1);
      *(ushort4*)(&bf1[i].u[4]) = *(const ushort4*)(p1 + 16);
      const ushort* p2 = Bs2 + (wc * 32 + i * 16 + lq) * 36 + g * 4;
      *(ushort4*)(&bf2[i].u[0]) = *(const ushort4*)(p2);
      *(ushort4*)(&bf2[i].u[4]) = *(const ushort4*)(p2 + 16);
    }
#pragma unroll
    for (int mi = 0; mi < 4; ++mi)
#pragma unroll
      for (int ni = 0; ni < 2; ++ni) {
        acc1[mi][ni] = __builtin_amdgcn_mfma_f32_16x16x32_bf16(
            af[mi].v, bf1[ni].v, acc1[mi][ni], 0, 0, 0);
        acc2[mi][ni] = __builtin_amdgcn_mfma_f32_16x16x32_bf16(
            af[mi].v, bf2[ni].v, acc2[mi][ni], 0, 0, 0);
      }
  }

#pragma unroll
  for (int mi = 0; mi < 4; ++mi)
#pragma unroll
    for (int ni = 0; ni < 2; ++ni) {
      const int n = n0 + wc * 32 + ni * 16 + lq;
      const float bv1 = b12[n];
      const float bv2 = b12[FFD + n];
#pragma unroll
      for (int r = 0; r < 4; ++r) {
        const int m = m0 + wr * 64 + mi * 16 + g * 4 + r;
        const float z1 = acc1[mi][ni][r] + bv1;
        const float z2 = acc2[mi][ni][r] + bv2;
        const float h = (z1 / (1.f + __expf(-z1))) * z2;
        hbb[(size_t)m * FFD + n] = f2bf(h);
      }
    }
}

// ---------------------------------------------------------------------------
// launch
// ---------------------------------------------------------------------------
extern "C" void kernel_launch(void* const* d_in, const int* in_sizes, int n_in,
                              void* d_out, int out_size, void* d_ws, size_t ws_size,
                              hipStream_t stream)
{
  const float* value = (const float*)d_in[0];
  const float* key   = (const float*)d_in[1];
  const float* query = (const float*)d_in[2];
  const int*   mask  = (const int*)d_in[3];
  const float* g1 = (const float*)d_in[4];
  const float* b1 = (const float*)d_in[5];
  const float* g2 = (const float*)d_in[6];
  const float* b2 = (const float*)d_in[7];
  const float* Wv = (const float*)d_in[8];
  const float* Wk = (const float*)d_in[9];
  const float* Wq = (const float*)d_in[10];
  const float* Wo = (const float*)d_in[11];
  const float* bo = (const float*)d_in[12];
  const float* W12 = (const float*)d_in[13];
  const float* b12 = (const float*)d_in[14];
  const float* W3  = (const float*)d_in[15];
  const float* b3  = (const float*)d_in[16];
  float* out = (float*)d_out;

  const size_t NE = (size_t)NTOK * EDIM;
  char* w = (char*)d_ws;
  ushort* qp   = (ushort*)w;              w += NE * 2;
  ushort* kp   = (ushort*)w;              w += NE * 2;
  ushort* vp   = (ushort*)w;              w += NE * 2;
  ushort* aob  = (ushort*)w;              w += NE * 2;
  ushort* Wob  = (ushort*)w;              w += (size_t)EDIM * EDIM * 2;
  ushort* W12b = (ushort*)w;              w += (size_t)2 * FFD * EDIM * 2;
  ushort* W3b  = (ushort*)w;              w += (size_t)EDIM * FFD * 2;
  float*  xb   = (float*)w;               w += NE * 4;
  ushort* xnb  = (ushort*)w;              w += NE * 2;
  ushort* hbb  = (ushort*)w;              w += (size_t)NTOK * FFD * 2;

  // 0) weight fp32 -> bf16
  k_f2b<<<(EDIM * EDIM / 4 + 255) / 256, 256, 0, stream>>>(Wo, Wob,
                                                           EDIM * EDIM / 4);
  k_f2b<<<(2 * FFD * EDIM / 4 + 255) / 256, 256, 0, stream>>>(W12, W12b,
                                                              2 * FFD * EDIM / 4);
  k_f2b<<<(EDIM * FFD / 4 + 255) / 256, 256, 0, stream>>>(W3, W3b,
                                                          EDIM * FFD / 4);
  // 1) LN1 + QKV head projections (bf16 out)
  k_ln_qkv<<<NTOK, 256, 0, stream>>>(query, key, value, g1, b1, Wq, Wk, Wv,
                                     qp, kp, vp);
  // 2) flash attention (bf16 out)
  k_attn_mfma<<<dim3(SEQ / 64, HN, BATCH), 256, 0, stream>>>(qp, kp, vp, mask,
                                                             aob);
  // 3) Wo projection + bias + residual(query) -> xb (fp32)
  k_gemm_bf<<<dim3(EDIM / 128, NTOK / 128), 256, 0, stream>>>(aob, Wob, bo,
                                                              query, xb, EDIM);
  // 4) LN2 -> xnb (bf16)
  k_ln<<<NTOK, 256, 0, stream>>>(xb, g2, b2, xnb);
  // 5) W12 + SwiGLU -> hbb (bf16)
  k_gemm_w12sw<<<dim3(FFD / 64, NTOK / 128), 256, 0, stream>>>(xnb, W12b, b12,
                                                               hbb);
  // 6) W3 + bias + residual(query) -> out (fp32)
  k_gemm_bf<<<dim3(EDIM / 128, NTOK / 128), 256, 0, stream>>>(hbb, W3b, b3,
                                                              query, out, FFD);
}

// Round 7
// 898.396 us; speedup vs baseline: 8.2454x; 1.0325x over previous
//
#include <hip/hip_runtime.h>
#include <math.h>

#define EDIM 1024
#define HN 16
#define HD 64
#define SEQ 2048
#define BATCH 4
#define FFD 4096
#define NTOK (BATCH*SEQ)

typedef __attribute__((ext_vector_type(8))) short bf16x8;
typedef __attribute__((ext_vector_type(4))) float f32x4;

union BF8 { bf16x8 v; ushort u[8]; };

__device__ __forceinline__ ushort f2bf(float f) {
  unsigned u = __float_as_uint(f);
  u += 0x7FFFu + ((u >> 16) & 1u);      // round-to-nearest-even
  return (ushort)(u >> 16);
}

// async global->LDS, 16B per lane; LDS dest = wave-uniform base + lane*16
__device__ __forceinline__ void gload16(const ushort* g, ushort* l) {
  __builtin_amdgcn_global_load_lds(
      (const __attribute__((address_space(1))) void*)g,
      (__attribute__((address_space(3))) void*)l, 16, 0, 0);
}

// ---------------------------------------------------------------------------
// Kernel 0: fp32 -> bf16 bulk convert (weights), n4 = elements/4
// ---------------------------------------------------------------------------
__global__ __launch_bounds__(256) void k_f2b(const float* __restrict__ s,
                                             ushort* __restrict__ d, int n4)
{
  const int i = blockIdx.x * 256 + threadIdx.x;
  if (i < n4) {
    float4 v = ((const float4*)s)[i];
    ushort4 o; o.x = f2bf(v.x); o.y = f2bf(v.y); o.z = f2bf(v.z); o.w = f2bf(v.w);
    ((ushort4*)d)[i] = o;
  }
}

// ---------------------------------------------------------------------------
// Kernel 1: fused LayerNorm(g1,b1) of q/k/v rows + per-head 64x64 projection.
// Outputs bf16 (consumed by MFMA attention).
// ---------------------------------------------------------------------------
__device__ __forceinline__ void proj_stage(const float* __restrict__ Wg,
                                           const float* xlds, float* wbuf,
                                           ushort* __restrict__ outp,
                                           size_t tE, int tid)
{
  for (int idx = tid; idx < HD * HD; idx += 256)
    wbuf[(idx >> 6) * 68 + (idx & 63)] = Wg[idx];
  __syncthreads();
  const int i = tid >> 2;
  const int g = tid & 3;
  const float4* wr = (const float4*)(wbuf + i * 68);
#pragma unroll
  for (int hh = 0; hh < 4; ++hh) {
    const int h = g * 4 + hh;
    const float4* xr = (const float4*)(xlds + h * 68);
    float acc = 0.f;
#pragma unroll
    for (int j4 = 0; j4 < 16; ++j4) {
      float4 w = wr[j4], x = xr[j4];
      acc += w.x * x.x + w.y * x.y + w.z * x.z + w.w * x.w;
    }
    outp[tE + h * 64 + i] = f2bf(acc);
  }
  __syncthreads();
}

__global__ __launch_bounds__(256) void k_ln_qkv(
    const float* __restrict__ qin, const float* __restrict__ kin,
    const float* __restrict__ vin, const float* __restrict__ g1,
    const float* __restrict__ b1, const float* __restrict__ Wq,
    const float* __restrict__ Wk, const float* __restrict__ Wv,
    ushort* __restrict__ qp, ushort* __restrict__ kp, ushort* __restrict__ vp)
{
  __shared__ float xq[HN * 68], xk[HN * 68], xv[HN * 68];
  __shared__ float wbuf[HD * 68];
  __shared__ float red[4][6];
  const int tid = threadIdx.x;
  const size_t tE = (size_t)blockIdx.x * EDIM;

  float4 aq = ((const float4*)(qin + tE))[tid];
  float4 ak = ((const float4*)(kin + tE))[tid];
  float4 av = ((const float4*)(vin + tE))[tid];

  float sq = aq.x + aq.y + aq.z + aq.w;
  float ssq = aq.x * aq.x + aq.y * aq.y + aq.z * aq.z + aq.w * aq.w;
  float sk = ak.x + ak.y + ak.z + ak.w;
  float ssk = ak.x * ak.x + ak.y * ak.y + ak.z * ak.z + ak.w * ak.w;
  float sv = av.x + av.y + av.z + av.w;
  float ssv = av.x * av.x + av.y * av.y + av.z * av.z + av.w * av.w;
#pragma unroll
  for (int off = 32; off; off >>= 1) {
    sq += __shfl_down(sq, off);   ssq += __shfl_down(ssq, off);
    sk += __shfl_down(sk, off);   ssk += __shfl_down(ssk, off);
    sv += __shfl_down(sv, off);   ssv += __shfl_down(ssv, off);
  }
  if ((tid & 63) == 0) {
    const int w = tid >> 6;
    red[w][0] = sq; red[w][1] = ssq; red[w][2] = sk;
    red[w][3] = ssk; red[w][4] = sv; red[w][5] = ssv;
  }
  __syncthreads();
  sq = red[0][0] + red[1][0] + red[2][0] + red[3][0];
  ssq = red[0][1] + red[1][1] + red[2][1] + red[3][1];
  sk = red[0][2] + red[1][2] + red[2][2] + red[3][2];
  ssk = red[0][3] + red[1][3] + red[2][3] + red[3][3];
  sv = red[0][4] + red[1][4] + red[2][4] + red[3][4];
  ssv = red[0][5] + red[1][5] + red[2][5] + red[3][5];

  const float rE = 1.f / EDIM;
  const float muq = sq * rE, muk = sk * rE, muv = sv * rE;
  const float ivq = rsqrtf(ssq * rE - muq * muq + 1e-5f);
  const float ivk = rsqrtf(ssk * rE - muk * muk + 1e-5f);
  const float ivv = rsqrtf(ssv * rE - muv * muv + 1e-5f);

  float4 gg = ((const float4*)g1)[tid];
  float4 bb = ((const float4*)b1)[tid];
  const int j = tid * 4;
  float* dq = xq + (j >> 6) * 68 + (j & 63);
  float* dk = xk + (j >> 6) * 68 + (j & 63);
  float* dv = xv + (j >> 6) * 68 + (j & 63);
  dq[0] = (aq.x - muq) * ivq * gg.x + bb.x;
  dq[1] = (aq.y - muq) * ivq * gg.y + bb.y;
  dq[2] = (aq.z - muq) * ivq * gg.z + bb.z;
  dq[3] = (aq.w - muq) * ivq * gg.w + bb.w;
  dk[0] = (ak.x - muk) * ivk * gg.x + bb.x;
  dk[1] = (ak.y - muk) * ivk * gg.y + bb.y;
  dk[2] = (ak.z - muk) * ivk * gg.z + bb.z;
  dk[3] = (ak.w - muk) * ivk * gg.w + bb.w;
  dv[0] = (av.x - muv) * ivv * gg.x + bb.x;
  dv[1] = (av.y - muv) * ivv * gg.y + bb.y;
  dv[2] = (av.z - muv) * ivv * gg.z + bb.z;
  dv[3] = (av.w - muv) * ivv * gg.w + bb.w;
  __syncthreads();

  proj_stage(Wq, xq, wbuf, qp, tE, tid);
  proj_stage(Wk, xk, wbuf, kp, tE, tid);
  proj_stage(Wv, xv, wbuf, vp, tE, tid);
}

// ---------------------------------------------------------------------------
// Kernel 2: flash attention, bf16 in (qp/kp/vp), bf16 out (aob). (unchanged)
// ---------------------------------------------------------------------------
__global__ __launch_bounds__(256) void k_attn_mfma(
    const ushort* __restrict__ qp, const ushort* __restrict__ kp,
    const ushort* __restrict__ vp, const int* __restrict__ maskp,
    ushort* __restrict__ aob)
{
  __shared__ ushort Klds[64 * 76];
  __shared__ ushort Vt[64 * 76];
  __shared__ int Ms[64];
  const int tid = threadIdx.x;
  const int wid = tid >> 6;
  const int lane = tid & 63;
  const int g = lane >> 4;
  const int lq = lane & 15;
  const int qt = blockIdx.x, h = blockIdx.y, b = blockIdx.z;
  const float slope = exp2f(-(float)(h + 1));
  const int q0 = qt * 64 + wid * 16;
  const size_t rowbase = (size_t)b * SEQ;
  const int colh = h * HD;

  BF8 qf[2];
  {
    const ushort* qrow = qp + (rowbase + q0 + lq) * EDIM + colh;
#pragma unroll
    for (int c = 0; c < 2; ++c) {
      *(ushort4*)(&qf[c].u[0]) = *(const ushort4*)(qrow + c * 32 + g * 4);
      *(ushort4*)(&qf[c].u[4]) = *(const ushort4*)(qrow + c * 32 + 16 + g * 4);
    }
  }

  f32x4 O[4];
#pragma unroll
  for (int d = 0; d < 4; ++d) O[d] = (f32x4){0.f, 0.f, 0.f, 0.f};
  float m_run = -1e30f, l_run = 0.f;
  const int qi = q0 + lq;

  for (int kt = 0; kt < SEQ / 64; ++kt) {
    const int kbase = kt * 64;
    __syncthreads();
#pragma unroll
    for (int u = 0; u < 2; ++u) {
      const int f = tid + u * 256;          // 512 chunks of 8 bf16
      const int key = f >> 3, c8 = f & 7;
      const ushort* ks = kp + (rowbase + kbase + key) * EDIM + colh + c8 * 8;
      ushort4 k0v = *(const ushort4*)ks;
      ushort4 k1v = *(const ushort4*)(ks + 4);
      *(ushort4*)(&Klds[key * 76 + c8 * 8]) = k0v;
      *(ushort4*)(&Klds[key * 76 + c8 * 8 + 4]) = k1v;
      const ushort* vs = vp + (rowbase + kbase + key) * EDIM + colh + c8 * 8;
      ushort4 v0 = *(const ushort4*)vs;
      ushort4 v1 = *(const ushort4*)(vs + 4);
      Vt[(c8 * 8 + 0) * 76 + key] = v0.x;
      Vt[(c8 * 8 + 1) * 76 + key] = v0.y;
      Vt[(c8 * 8 + 2) * 76 + key] = v0.z;
      Vt[(c8 * 8 + 3) * 76 + key] = v0.w;
      Vt[(c8 * 8 + 4) * 76 + key] = v1.x;
      Vt[(c8 * 8 + 5) * 76 + key] = v1.y;
      Vt[(c8 * 8 + 6) * 76 + key] = v1.z;
      Vt[(c8 * 8 + 7) * 76 + key] = v1.w;
    }
    if (tid < 64) Ms[tid] = maskp[b * SEQ + kbase + tid];
    __syncthreads();

    f32x4 sT[4];
#pragma unroll
    for (int kb = 0; kb < 4; ++kb) {
      sT[kb] = (f32x4){0.f, 0.f, 0.f, 0.f};
#pragma unroll
      for (int c = 0; c < 2; ++c) {
        BF8 a;
        const ushort* src = &Klds[(kb * 16 + lq) * 76 + c * 32 + g * 4];
        *(ushort4*)(&a.u[0]) = *(const ushort4*)(src);
        *(ushort4*)(&a.u[4]) = *(const ushort4*)(src + 16);
        sT[kb] = __builtin_amdgcn_mfma_f32_16x16x32_bf16(a.v, qf[c].v, sT[kb],
                                                         0, 0, 0);
      }
    }

    float pv[16];
    float mt = -1e30f;
#pragma unroll
    for (int kb = 0; kb < 4; ++kb)
#pragma unroll
      for (int r = 0; r < 4; ++r) {
        const int kloc = kb * 16 + g * 4 + r;
        const float dist = fabsf((float)(qi - (kbase + kloc)));
        const float s = Ms[kloc] ? (sT[kb][r] - slope * dist) * 0.03125f
                                 : -312.5f;
        pv[kb * 4 + r] = s;
        mt = fmaxf(mt, s);
      }
    mt = fmaxf(mt, __shfl_xor(mt, 16));
    mt = fmaxf(mt, __shfl_xor(mt, 32));
    const float mn = fmaxf(m_run, mt);
    const float corr = __expf(m_run - mn);
    m_run = mn;

    float sum = 0.f;
    BF8 pa[2];
#pragma unroll
    for (int idx = 0; idx < 16; ++idx) {
      const float p = __expf(pv[idx] - mn);
      sum += p;
      pa[idx >> 3].u[idx & 7] = f2bf(p);
    }
    sum += __shfl_xor(sum, 16);
    sum += __shfl_xor(sum, 32);
    l_run = l_run * corr + sum;

    float corrO[4];
#pragma unroll
    for (int r = 0; r < 4; ++r) corrO[r] = __shfl(corr, g * 4 + r);
#pragma unroll
    for (int d = 0; d < 4; ++d)
#pragma unroll
      for (int r = 0; r < 4; ++r) O[d][r] *= corrO[r];

#pragma unroll
    for (int d = 0; d < 4; ++d) {
#pragma unroll
      for (int c = 0; c < 2; ++c) {
        BF8 vb;
        const ushort* vsrc = &Vt[(d * 16 + lq) * 76 + c * 32 + g * 4];
        *(ushort4*)(&vb.u[0]) = *(const ushort4*)(vsrc);
        *(ushort4*)(&vb.u[4]) = *(const ushort4*)(vsrc + 16);
        O[d] = __builtin_amdgcn_mfma_f32_16x16x32_bf16(pa[c].v, vb.v, O[d],
                                                       0, 0, 0);
      }
    }
  }

  float linv[4];
#pragma unroll
  for (int r = 0; r < 4; ++r) linv[r] = 1.f / __shfl(l_run, g * 4 + r);
#pragma unroll
  for (int d = 0; d < 4; ++d)
#pragma unroll
    for (int r = 0; r < 4; ++r)
      aob[(rowbase + q0 + g * 4 + r) * EDIM + colh + d * 16 + lq] =
          f2bf(O[d][r] * linv[r]);
}

// ---------------------------------------------------------------------------
// Kernel 3: bf16 MFMA GEMM, m97 structure: global_load_lds(16B) staging into
// LINEAR LDS [row][32], contiguous k-perm (lane(g,lq) <-> k=8g..8g+7) so each
// fragment is one ds_read_b128. 128x128 tile, BK=32, 2-barrier loop.
// ---------------------------------------------------------------------------
__global__ __launch_bounds__(256) void k_gemm_bf(
    const ushort* __restrict__ A, const ushort* __restrict__ W,
    const float* __restrict__ bias, const float* __restrict__ resid,
    float* __restrict__ out, int K)
{
  __shared__ __align__(16) ushort As[128 * 32];
  __shared__ __align__(16) ushort Bs[128 * 32];
  const int tid = threadIdx.x;
  const int wid = tid >> 6, lane = tid & 63;
  const int g = lane >> 4, lq = lane & 15;
  const int m0 = blockIdx.y * 128, n0 = blockIdx.x * 128;
  const int wr = wid >> 1, wc = wid & 1;
  const int srow = lane >> 2;          // 0..15 within a 16-row chunk
  const int scol = (lane & 3) * 8;     // bf16 elems within a 32-elem row

  f32x4 acc[4][4];
#pragma unroll
  for (int mi = 0; mi < 4; ++mi)
#pragma unroll
    for (int ni = 0; ni < 4; ++ni) acc[mi][ni] = (f32x4){0.f, 0.f, 0.f, 0.f};

  for (int k0 = 0; k0 < K; k0 += 32) {
    __syncthreads();             // prev tile fully consumed
#pragma unroll
    for (int c = 0; c < 2; ++c) {
      const int r = wid * 32 + c * 16;   // wave-uniform row base
      gload16(A + (size_t)(m0 + r + srow) * K + k0 + scol, &As[r * 32]);
      gload16(W + (size_t)(n0 + r + srow) * K + k0 + scol, &Bs[r * 32]);
    }
    __syncthreads();             // drains vmcnt -> LDS visible

    BF8 af[4], bf[4];
#pragma unroll
    for (int i = 0; i < 4; ++i) {
      af[i].v = *(const bf16x8*)(&As[(wr * 64 + i * 16 + lq) * 32 + g * 8]);
      bf[i].v = *(const bf16x8*)(&Bs[(wc * 64 + i * 16 + lq) * 32 + g * 8]);
    }
#pragma unroll
    for (int mi = 0; mi < 4; ++mi)
#pragma unroll
      for (int ni = 0; ni < 4; ++ni)
        acc[mi][ni] = __builtin_amdgcn_mfma_f32_16x16x32_bf16(
            af[mi].v, bf[ni].v, acc[mi][ni], 0, 0, 0);
  }

#pragma unroll
  for (int mi = 0; mi < 4; ++mi)
#pragma unroll
    for (int ni = 0; ni < 4; ++ni) {
      const int n = n0 + wc * 64 + ni * 16 + lq;
      const float bv = bias[n];
#pragma unroll
      for (int r = 0; r < 4; ++r) {
        const int m = m0 + wr * 64 + mi * 16 + g * 4 + r;
        out[(size_t)m * EDIM + n] =
            acc[mi][ni][r] + bv + resid[(size_t)m * EDIM + n];
      }
    }
}

// ---------------------------------------------------------------------------
// Kernel 4: LayerNorm, fp32 in -> bf16 out (one block per token)
// ---------------------------------------------------------------------------
__global__ __launch_bounds__(256) void k_ln(
    const float* __restrict__ x, const float* __restrict__ g,
    const float* __restrict__ bb, ushort* __restrict__ y)
{
  __shared__ float red[4][2];
  const int tid = threadIdx.x;
  const size_t tE = (size_t)blockIdx.x * EDIM;
  float4 v = ((const float4*)(x + tE))[tid];
  float s = v.x + v.y + v.z + v.w;
  float ss = v.x * v.x + v.y * v.y + v.z * v.z + v.w * v.w;
#pragma unroll
  for (int off = 32; off; off >>= 1) {
    s += __shfl_down(s, off); ss += __shfl_down(ss, off);
  }
  if ((tid & 63) == 0) { red[tid >> 6][0] = s; red[tid >> 6][1] = ss; }
  __syncthreads();
  s = red[0][0] + red[1][0] + red[2][0] + red[3][0];
  ss = red[0][1] + red[1][1] + red[2][1] + red[3][1];
  const float mu = s * (1.f / EDIM);
  const float inv = rsqrtf(ss * (1.f / EDIM) - mu * mu + 1e-5f);
  float4 gg = ((const float4*)g)[tid];
  float4 b4 = ((const float4*)bb)[tid];
  ushort4 o;
  o.x = f2bf((v.x - mu) * inv * gg.x + b4.x);
  o.y = f2bf((v.y - mu) * inv * gg.y + b4.y);
  o.z = f2bf((v.z - mu) * inv * gg.z + b4.z);
  o.w = f2bf((v.w - mu) * inv * gg.w + b4.w);
  *(ushort4*)(y + tE + tid * 4) = o;
}

// ---------------------------------------------------------------------------
// Kernel 5: W12 bf16 MFMA GEMM + fused SwiGLU, m97-style staging.
// Tile 128m x (64 x1-cols + 64 x2-cols), BK=32. Waves 0-1 stage As,
// wave 2 stages Bs1, wave 3 stages Bs2 (4 gload16 each).
// ---------------------------------------------------------------------------
__global__ __launch_bounds__(256) void k_gemm_w12sw(
    const ushort* __restrict__ A, const ushort* __restrict__ W12,
    const float* __restrict__ b12, ushort* __restrict__ hbb)
{
  __shared__ __align__(16) ushort As[128 * 32];
  __shared__ __align__(16) ushort Bs1[64 * 32];
  __shared__ __align__(16) ushort Bs2[64 * 32];
  const int tid = threadIdx.x;
  const int wid = tid >> 6, lane = tid & 63;
  const int g = lane >> 4, lq = lane & 15;
  const int m0 = blockIdx.y * 128, n0 = blockIdx.x * 64;
  const int wr = wid >> 1, wc = wid & 1;
  const int srow = lane >> 2;
  const int scol = (lane & 3) * 8;

  f32x4 acc1[4][2], acc2[4][2];
#pragma unroll
  for (int mi = 0; mi < 4; ++mi)
#pragma unroll
    for (int ni = 0; ni < 2; ++ni) {
      acc1[mi][ni] = (f32x4){0.f, 0.f, 0.f, 0.f};
      acc2[mi][ni] = (f32x4){0.f, 0.f, 0.f, 0.f};
    }

  for (int k0 = 0; k0 < EDIM; k0 += 32) {
    __syncthreads();
    if (wid < 2) {
#pragma unroll
      for (int c = 0; c < 4; ++c) {
        const int r = wid * 64 + c * 16;
        gload16(A + (size_t)(m0 + r + srow) * EDIM + k0 + scol, &As[r * 32]);
      }
    } else if (wid == 2) {
#pragma unroll
      for (int c = 0; c < 4; ++c)
        gload16(W12 + (size_t)(n0 + c * 16 + srow) * EDIM + k0 + scol,
                &Bs1[(c * 16) * 32]);
    } else {
#pragma unroll
      for (int c = 0; c < 4; ++c)
        gload16(W12 + (size_t)(FFD + n0 + c * 16 + srow) * EDIM + k0 + scol,
                &Bs2[(c * 16) * 32]);
    }
    __syncthreads();

    BF8 af[4], bf1[2], bf2[2];
#pragma unroll
    for (int i = 0; i < 4; ++i)
      af[i].v = *(const bf16x8*)(&As[(wr * 64 + i * 16 + lq) * 32 + g * 8]);
#pragma unroll
    for (int i = 0; i < 2; ++i) {
      bf1[i].v = *(const bf16x8*)(&Bs1[(wc * 32 + i * 16 + lq) * 32 + g * 8]);
      bf2[i].v = *(const bf16x8*)(&Bs2[(wc * 32 + i * 16 + lq) * 32 + g * 8]);
    }
#pragma unroll
    for (int mi = 0; mi < 4; ++mi)
#pragma unroll
      for (int ni = 0; ni < 2; ++ni) {
        acc1[mi][ni] = __builtin_amdgcn_mfma_f32_16x16x32_bf16(
            af[mi].v, bf1[ni].v, acc1[mi][ni], 0, 0, 0);
        acc2[mi][ni] = __builtin_amdgcn_mfma_f32_16x16x32_bf16(
            af[mi].v, bf2[ni].v, acc2[mi][ni], 0, 0, 0);
      }
  }

#pragma unroll
  for (int mi = 0; mi < 4; ++mi)
#pragma unroll
    for (int ni = 0; ni < 2; ++ni) {
      const int n = n0 + wc * 32 + ni * 16 + lq;
      const float bv1 = b12[n];
      const float bv2 = b12[FFD + n];
#pragma unroll
      for (int r = 0; r < 4; ++r) {
        const int m = m0 + wr * 64 + mi * 16 + g * 4 + r;
        const float z1 = acc1[mi][ni][r] + bv1;
        const float z2 = acc2[mi][ni][r] + bv2;
        const float h = (z1 / (1.f + __expf(-z1))) * z2;
        hbb[(size_t)m * FFD + n] = f2bf(h);
      }
    }
}

// ---------------------------------------------------------------------------
// launch
// ---------------------------------------------------------------------------
extern "C" void kernel_launch(void* const* d_in, const int* in_sizes, int n_in,
                              void* d_out, int out_size, void* d_ws, size_t ws_size,
                              hipStream_t stream)
{
  const float* value = (const float*)d_in[0];
  const float* key   = (const float*)d_in[1];
  const float* query = (const float*)d_in[2];
  const int*   mask  = (const int*)d_in[3];
  const float* g1 = (const float*)d_in[4];
  const float* b1 = (const float*)d_in[5];
  const float* g2 = (const float*)d_in[6];
  const float* b2 = (const float*)d_in[7];
  const float* Wv = (const float*)d_in[8];
  const float* Wk = (const float*)d_in[9];
  const float* Wq = (const float*)d_in[10];
  const float* Wo = (const float*)d_in[11];
  const float* bo = (const float*)d_in[12];
  const float* W12 = (const float*)d_in[13];
  const float* b12 = (const float*)d_in[14];
  const float* W3  = (const float*)d_in[15];
  const float* b3  = (const float*)d_in[16];
  float* out = (float*)d_out;

  const size_t NE = (size_t)NTOK * EDIM;
  char* w = (char*)d_ws;
  ushort* qp   = (ushort*)w;              w += NE * 2;
  ushort* kp   = (ushort*)w;              w += NE * 2;
  ushort* vp   = (ushort*)w;              w += NE * 2;
  ushort* aob  = (ushort*)w;              w += NE * 2;
  ushort* Wob  = (ushort*)w;              w += (size_t)EDIM * EDIM * 2;
  ushort* W12b = (ushort*)w;              w += (size_t)2 * FFD * EDIM * 2;
  ushort* W3b  = (ushort*)w;              w += (size_t)EDIM * FFD * 2;
  float*  xb   = (float*)w;               w += NE * 4;
  ushort* xnb  = (ushort*)w;              w += NE * 2;
  ushort* hbb  = (ushort*)w;              w += (size_t)NTOK * FFD * 2;

  // 0) weight fp32 -> bf16
  k_f2b<<<(EDIM * EDIM / 4 + 255) / 256, 256, 0, stream>>>(Wo, Wob,
                                                           EDIM * EDIM / 4);
  k_f2b<<<(2 * FFD * EDIM / 4 + 255) / 256, 256, 0, stream>>>(W12, W12b,
                                                              2 * FFD * EDIM / 4);
  k_f2b<<<(EDIM * FFD / 4 + 255) / 256, 256, 0, stream>>>(W3, W3b,
                                                          EDIM * FFD / 4);
  // 1) LN1 + QKV head projections (bf16 out)
  k_ln_qkv<<<NTOK, 256, 0, stream>>>(query, key, value, g1, b1, Wq, Wk, Wv,
                                     qp, kp, vp);
  // 2) flash attention (bf16 out)
  k_attn_mfma<<<dim3(SEQ / 64, HN, BATCH), 256, 0, stream>>>(qp, kp, vp, mask,
                                                             aob);
  // 3) Wo projection + bias + residual(query) -> xb (fp32)
  k_gemm_bf<<<dim3(EDIM / 128, NTOK / 128), 256, 0, stream>>>(aob, Wob, bo,
                                                              query, xb, EDIM);
  // 4) LN2 -> xnb (bf16)
  k_ln<<<NTOK, 256, 0, stream>>>(xb, g2, b2, xnb);
  // 5) W12 + SwiGLU -> hbb (bf16)
  k_gemm_w12sw<<<dim3(FFD / 64, NTOK / 128), 256, 0, stream>>>(xnb, W12b, b12,
                                                               hbb);
  // 6) W3 + bias + residual(query) -> out (fp32)
  k_gemm_bf<<<dim3(EDIM / 128, NTOK / 128), 256, 0, stream>>>(hbb, W3b, b3,
                                                              query, out, FFD);
}